// Round 6
// baseline (3423.991 us; speedup 1.0000x reference)
//
#include <hip/hip_runtime.h>
#include <cstdint>
#include <cstddef>

#define HD 128
#define EMBD 96
#define SELD 32
#define PD 64
#define NPOS 513
#define GITERS 6

typedef __attribute__((ext_vector_type(8))) short bf16x8;
typedef __attribute__((ext_vector_type(4))) float f32x4;

__device__ __forceinline__ float sigm(float x) { return 1.0f / (1.0f + __expf(-x)); }

__device__ __forceinline__ short f2bf(float x) {
    uint32_t u = __float_as_uint(x);
    uint32_t r = (u + 0x7fffu + ((u >> 16) & 1u)) >> 16;
    return (short)r;
}
__device__ __forceinline__ float bf2f(uint32_t s) {
    return __uint_as_float(s << 16);
}

// ---------------- setup kernels ----------------

__global__ void k_deg(const int* __restrict__ ei, const int* __restrict__ et,
                      int* __restrict__ deg, int* __restrict__ cnt_t, int E, int N) {
    int e = blockIdx.x * 256 + threadIdx.x;
    if (e < E) {
        int d = ei[E + e];
        atomicAdd(&deg[d], 1);
        atomicAdd(&cnt_t[(size_t)et[e] * N + d], 1);
    }
}

__global__ void k_cntp(const int* __restrict__ deg, const int* __restrict__ cnt_t,
                       float4* __restrict__ cntp, int N) {
    int n = blockIdx.x * 256 + threadIdx.x;
    if (n < N) {
        float4 v;
        v.x = (float)cnt_t[n];
        v.y = (float)cnt_t[(size_t)N + n];
        v.z = (float)cnt_t[2 * (size_t)N + n];
        v.w = 1.0f / fmaxf((float)deg[n], 1.0f);
        cntp[n] = v;
    }
}

__launch_bounds__(1024)
__global__ void k_scan(const int* __restrict__ deg, int* __restrict__ rp, int N, int E) {
    __shared__ int sc[1024];
    int t = threadIdx.x;
    int chunk = (N + 1023) / 1024;
    int lo = t * chunk, hi = min(N, lo + chunk);
    int sum = 0;
    for (int i = lo; i < hi; ++i) sum += deg[i];
    sc[t] = sum;
    __syncthreads();
    for (int off = 1; off < 1024; off <<= 1) {
        int v = (t >= off) ? sc[t - off] : 0;
        __syncthreads();
        sc[t] += v;
        __syncthreads();
    }
    int base = sc[t] - sum;
    int run = base;
    for (int i = lo; i < hi; ++i) { rp[i] = run; run += deg[i]; }
    if (t == 1023) rp[N] = base + sum;
}

// epack: (dst&31)<<13 | type<<10 | pos   (32-row block tiles are fixed)
__global__ void k_fill(const int* __restrict__ ei, const int* __restrict__ et,
                       const int* __restrict__ ep, const int* __restrict__ rp,
                       int* __restrict__ cursor, int* __restrict__ esrc,
                       int* __restrict__ epack, int E) {
    int e = blockIdx.x * 256 + threadIdx.x;
    if (e < E) {
        int d = ei[E + e];
        int pos = atomicAdd(&cursor[d], 1);
        int idx = rp[d] + pos;
        esrc[idx] = ei[e];
        epack[idx] = ((d & 31) << 13) | (et[e] << 10) | ep[e];
    }
}

__global__ void k_gate(const float* __restrict__ pe, const float* __restrict__ Wg,
                       const float* __restrict__ bg, short* __restrict__ gb) {
    int p = blockIdx.x;
    int j = threadIdx.x;
    float acc = bg[j];
    #pragma unroll 8
    for (int k = 0; k < PD; ++k) acc += pe[p * PD + k] * Wg[k * HD + j];
    gb[p * HD + j] = f2bf(2.0f * sigm(acc));
}

__global__ void k_prep(const float* __restrict__ Wt, const float* __restrict__ Wih,
                       const float* __restrict__ Whh, const float* __restrict__ W1,
                       short* __restrict__ WtT, short* __restrict__ Wihb,
                       short* __restrict__ Whhb, short* __restrict__ W1T) {
    const int SZ = 3 * HD * HD;
    int id = blockIdx.x * 256 + threadIdx.x;
    if (id < SZ) {
        int t = id / (HD * HD), rem = id % (HD * HD);
        int n = rem / HD, k = rem % HD;
        WtT[id] = f2bf(Wt[t * HD * HD + k * HD + n]);
    } else if (id < 2 * SZ) {
        int i2 = id - SZ;
        Wihb[i2] = f2bf(Wih[i2]);
    } else if (id < 3 * SZ) {
        int i2 = id - 2 * SZ;
        Whhb[i2] = f2bf(Whh[i2]);
    } else if (id < 3 * SZ + 2 * HD * HD) {
        int rem = id - 3 * SZ;
        int n = rem / (2 * HD), k = rem % (2 * HD);
        W1T[rem] = f2bf(W1[k * HD + n]);
    }
}

__global__ void k_init(const int* __restrict__ xidx, const float* __restrict__ sel,
                       const float* __restrict__ emb, float* __restrict__ h,
                       short* __restrict__ h_bf, int N) {
    int id = blockIdx.x * 256 + threadIdx.x;
    if (id < N * HD) {
        int n = id >> 7, j = id & 127;
        float v = (j < EMBD) ? emb[(size_t)xidx[n] * EMBD + j]
                             : sel[(size_t)n * SELD + (j - EMBD)];
        h[id] = v;
        h_bf[id] = f2bf(v);
    }
}

// ---------------- fused per-iteration kernel ----------------
// 32 dst rows / block, 1024 threads = 16 waves. wave = (tile tau, colgroup cg).
// P0: zero f32 scatter buffer S.
// P1: edge-cooperative gather: the block's contiguous CSR edge range is split
//     evenly across waves; per edge: h/gate loads + 2 LDS float atomics.
// P2: per wave: h@Whh (A from global h_in, regs) + agg MFMA (A from S) -> aggL.
// P3: agg@Wih + combine + GRU epilogue (h fp32 prefetched) -> h, h_out.
#define SSTR 130
#define ASTR 136
__launch_bounds__(1024, 8)
__global__ void k_iter(const int* __restrict__ rp, const int* __restrict__ esrc,
                       const int* __restrict__ epack, const short* __restrict__ h_in,
                       const short* __restrict__ gb, const short* __restrict__ WtT,
                       const float* __restrict__ bt, const float4* __restrict__ cntp,
                       const short* __restrict__ Wihb, const short* __restrict__ Whhb,
                       const float* __restrict__ bih, const float* __restrict__ bhh,
                       float* __restrict__ h, short* __restrict__ h_out, int N) {
    __shared__ float S[3 * 32 * SSTR];    // 49,920 B
    __shared__ short aggL[32 * ASTR];     //  8,704 B

    int tid = threadIdx.x;
    int wave = tid >> 6, lane = tid & 63;
    int quad = lane >> 4, m = lane & 15;
    int d0 = blockIdx.x * 32;
    int tau = wave >> 3, cg = wave & 7;
    int col = cg * 16 + m;

    // prefetch fp32 h for the epilogue (hides HBM latency behind gather)
    float hpre[4];
    #pragma unroll
    for (int r = 0; r < 4; ++r) {
        int grow = min(d0 + tau * 16 + quad * 4 + r, N - 1);
        hpre[r] = h[(size_t)grow * HD + col];
    }

    // ---- P0: zero S
    for (int i = tid; i < 3 * 32 * SSTR; i += 1024) S[i] = 0.0f;
    __syncthreads();

    // ---- P1: edge-cooperative gather
    {
        int es = __builtin_amdgcn_readfirstlane(rp[min(d0, N)]);
        int ee = __builtin_amdgcn_readfirstlane(rp[min(d0 + 32, N)]);
        int K = ee - es;
        int cpw = (K + 15) >> 4;
        int e = es + wave * cpw;
        int hi = min(ee, e + cpw);
        int cl = 2 * lane;
        #define EDGE(sv, pv)                                                  \
            {                                                                 \
                int dl = (pv) >> 13;                                          \
                int tt = ((pv) >> 10) & 3;                                    \
                uint32_t hv = *(const uint32_t*)(h_in + (size_t)(sv) * HD + cl); \
                uint32_t gv = *(const uint32_t*)(gb + (size_t)((pv) & 1023) * HD + cl); \
                float mx = bf2f(hv & 0xffffu) * bf2f(gv & 0xffffu);           \
                float my = bf2f(hv >> 16) * bf2f(gv >> 16);                   \
                float* Sp = S + ((tt << 5) + dl) * SSTR + cl;                 \
                atomicAdd(Sp, mx);                                            \
                atomicAdd(Sp + 1, my);                                        \
            }
        for (; e + 4 <= hi; e += 4) {
            int s0 = esrc[e],  s1 = esrc[e + 1], s2 = esrc[e + 2], s3 = esrc[e + 3];
            int p0 = epack[e], p1 = epack[e + 1], p2 = epack[e + 2], p3 = epack[e + 3];
            EDGE(s0, p0); EDGE(s1, p1); EDGE(s2, p2); EDGE(s3, p3);
        }
        for (; e < hi; ++e) {
            int s0 = esrc[e];
            int p0 = epack[e];
            EDGE(s0, p0);
        }
        #undef EDGE
    }

    // ---- P2a (pre-barrier part): h @ Whh, A-frags straight from global h_in
    int garow = min(d0 + tau * 16 + m, N - 1);
    bf16x8 fh[4];
    #pragma unroll
    for (int c = 0; c < 4; ++c)
        fh[c] = *(const bf16x8*)(h_in + (size_t)garow * HD + c * 32 + quad * 8);
    f32x4 ah[3];
    const f32x4 z4 = {0.f, 0.f, 0.f, 0.f};
    ah[0] = z4; ah[1] = z4; ah[2] = z4;
    #pragma unroll
    for (int g = 0; g < 3; ++g)
        #pragma unroll
        for (int c = 0; c < 4; ++c) {
            bf16x8 b = *(const bf16x8*)(Whhb + ((size_t)g * HD + col) * HD + c * 32 + quad * 8);
            ah[g] = __builtin_amdgcn_mfma_f32_16x16x32_bf16(fh[c], b, ah[g], 0, 0, 0);
        }

    __syncthreads();  // gather complete

    // ---- P2b: agg MFMA from S (f32 -> bf16 inline) -> aggL
    {
        f32x4 acc = z4;
        #pragma unroll
        for (int t = 0; t < 3; ++t)
            #pragma unroll
            for (int c = 0; c < 4; ++c) {
                const float* sp = S + ((t << 5) + tau * 16 + m) * SSTR + c * 32 + quad * 8;
                bf16x8 a;
                #pragma unroll
                for (int j = 0; j < 8; ++j) a[j] = f2bf(sp[j]);
                bf16x8 b = *(const bf16x8*)(WtT + ((size_t)t * HD + col) * HD + c * 32 + quad * 8);
                acc = __builtin_amdgcn_mfma_f32_16x16x32_bf16(a, b, acc, 0, 0, 0);
            }
        float bt0 = bt[col], bt1 = bt[HD + col], bt2 = bt[2 * HD + col];
        #pragma unroll
        for (int r = 0; r < 4; ++r) {
            int lr = tau * 16 + quad * 4 + r;
            int dd = min(d0 + lr, N - 1);
            float4 cp = cntp[dd];
            float v = (acc[r] + cp.x * bt0 + cp.y * bt1 + cp.z * bt2) * cp.w;
            aggL[lr * ASTR + col] = f2bf(v);
        }
    }
    __syncthreads();  // aggL complete

    // ---- P3: agg @ Wih + combine + GRU epilogue
    {
        bf16x8 fa[4];
        #pragma unroll
        for (int c = 0; c < 4; ++c)
            fa[c] = *(const bf16x8*)(aggL + (tau * 16 + m) * ASTR + c * 32 + quad * 8);
        f32x4 ai[3];
        ai[0] = z4; ai[1] = z4; ai[2] = z4;
        #pragma unroll
        for (int g = 0; g < 3; ++g)
            #pragma unroll
            for (int c = 0; c < 4; ++c) {
                bf16x8 b = *(const bf16x8*)(Wihb + ((size_t)g * HD + col) * HD + c * 32 + quad * 8);
                ai[g] = __builtin_amdgcn_mfma_f32_16x16x32_bf16(fa[c], b, ai[g], 0, 0, 0);
            }

        float bir = bih[col],          bhr = bhh[col];
        float biz = bih[HD + col],     bhz = bhh[HD + col];
        float bin = bih[2 * HD + col], bhn = bhh[2 * HD + col];
        #pragma unroll
        for (int r = 0; r < 4; ++r) {
            int grow = d0 + tau * 16 + quad * 4 + r;
            if (grow < N) {
                float rr = sigm(ai[0][r] + bir + ah[0][r] + bhr);
                float zz = sigm(ai[1][r] + biz + ah[1][r] + bhz);
                float nn = tanhf(ai[2][r] + bin + rr * (ah[2][r] + bhn));
                float hp = (1.0f - zz) * nn + zz * hpre[r];
                size_t idx = (size_t)grow * HD + col;
                h[idx] = hp;
                h_out[idx] = f2bf(hp);
            }
        }
    }
}

// feats=[h|emb[x]|sel] (bf16 frags) @ W1T (MFMA) -> relu -> @W2 + b2
__launch_bounds__(256)
__global__ void k_final(const short* __restrict__ h_bf, const int* __restrict__ xidx,
                        const float* __restrict__ sel, const float* __restrict__ emb,
                        const short* __restrict__ W1T, const float* __restrict__ b1,
                        const float* __restrict__ W2, const float* __restrict__ b2,
                        float* __restrict__ out, int N) {
    __shared__ float red[4][16];
    int tid = threadIdx.x;
    int wave = tid >> 6, lane = tid & 63;
    int quad = lane >> 4, m = lane & 15;
    int row0 = blockIdx.x * 16;
    int arow = min(row0 + m, N - 1);
    int xi = xidx[arow];

    bf16x8 fa[8];
    #pragma unroll
    for (int c = 0; c < 4; ++c)
        fa[c] = *(const bf16x8*)(h_bf + (size_t)arow * HD + c * 32 + quad * 8);
    #pragma unroll
    for (int c = 4; c < 7; ++c) {
        const float* ep = emb + (size_t)xi * EMBD + (c - 4) * 32 + quad * 8;
        #pragma unroll
        for (int j = 0; j < 8; ++j) fa[c][j] = f2bf(ep[j]);
    }
    {
        const float* sp = sel + (size_t)arow * SELD + quad * 8;
        #pragma unroll
        for (int j = 0; j < 8; ++j) fa[7][j] = f2bf(sp[j]);
    }

    f32x4 acc[2];
    const f32x4 z4 = {0.f, 0.f, 0.f, 0.f};
    acc[0] = z4; acc[1] = z4;
    #pragma unroll
    for (int s = 0; s < 2; ++s) {
        int c0 = (wave * 2 + s) * 16;
        #pragma unroll
        for (int c = 0; c < 8; ++c) {
            bf16x8 b = *(const bf16x8*)(W1T + (size_t)(c0 + m) * (2 * HD) + c * 32 + quad * 8);
            acc[s] = __builtin_amdgcn_mfma_f32_16x16x32_bf16(fa[c], b, acc[s], 0, 0, 0);
        }
    }

    float psum[4] = {0.f, 0.f, 0.f, 0.f};
    #pragma unroll
    for (int s = 0; s < 2; ++s) {
        int col = (wave * 2 + s) * 16 + m;
        float b1v = b1[col], w2v = W2[col];
        #pragma unroll
        for (int r = 0; r < 4; ++r)
            psum[r] += fmaxf(acc[s][r] + b1v, 0.0f) * w2v;
    }
    #pragma unroll
    for (int off = 1; off < 16; off <<= 1)
        #pragma unroll
        for (int r = 0; r < 4; ++r) psum[r] += __shfl_xor(psum[r], off);

    if (m == 0) {
        #pragma unroll
        for (int r = 0; r < 4; ++r) red[wave][quad * 4 + r] = psum[r];
    }
    __syncthreads();
    if (tid < 16) {
        int row = row0 + tid;
        if (row < N) out[row] = red[0][tid] + red[1][tid] + red[2][tid] + red[3][tid] + b2[0];
    }
}

// ---------------- launcher ----------------

extern "C" void kernel_launch(void* const* d_in, const int* in_sizes, int n_in,
                              void* d_out, int out_size, void* d_ws, size_t ws_size,
                              hipStream_t stream) {
    const int*   xidx = (const int*)d_in[0];
    const float* sel  = (const float*)d_in[1];
    const int*   ei   = (const int*)d_in[2];
    const int*   et   = (const int*)d_in[3];
    const int*   ep   = (const int*)d_in[4];
    const float* emb  = (const float*)d_in[5];
    const float* pe   = (const float*)d_in[6];
    const float* Wg   = (const float*)d_in[7];
    const float* bg   = (const float*)d_in[8];
    const float* Wt   = (const float*)d_in[9];
    const float* bt   = (const float*)d_in[10];
    const float* Wih  = (const float*)d_in[11];
    const float* Whh  = (const float*)d_in[12];
    const float* bih  = (const float*)d_in[13];
    const float* bhh  = (const float*)d_in[14];
    const float* W1   = (const float*)d_in[15];
    const float* b1   = (const float*)d_in[16];
    const float* W2   = (const float*)d_in[17];
    const float* b2   = (const float*)d_in[18];

    const int N = in_sizes[0];
    const int E = in_sizes[3];
    const size_t NH = (size_t)N * HD;

    char* p = (char*)d_ws;
    float*  h     = (float*)p;  p += NH * 4;
    short*  hbf0  = (short*)p;  p += NH * 2;
    short*  hbf1  = (short*)p;  p += NH * 2;
    short*  gb    = (short*)p;  p += (size_t)NPOS * HD * 2;
    short*  WtT   = (short*)p;  p += 3 * HD * HD * 2;
    short*  Wihb  = (short*)p;  p += 3 * HD * HD * 2;
    short*  Whhb  = (short*)p;  p += 3 * HD * HD * 2;
    short*  W1T   = (short*)p;  p += 2 * HD * HD * 2;
    float4* cntp  = (float4*)p; p += (size_t)N * 16;
    int* deg    = (int*)p; p += (size_t)N * 4;
    int* cnt_t  = (int*)p; p += 3 * (size_t)N * 4;
    int* rp     = (int*)p; p += (size_t)(N + 1) * 4;
    int* cursor = (int*)p; p += (size_t)N * 4;
    int* esrc   = (int*)p; p += (size_t)E * 4;
    int* epack  = (int*)p;

    // ---- setup ----
    hipMemsetAsync(deg, 0, (size_t)N * sizeof(int), stream);
    hipMemsetAsync(cnt_t, 0, 3 * (size_t)N * sizeof(int), stream);
    hipMemsetAsync(cursor, 0, (size_t)N * sizeof(int), stream);
    k_deg<<<(E + 255) / 256, 256, 0, stream>>>(ei, et, deg, cnt_t, E, N);
    k_cntp<<<(N + 255) / 256, 256, 0, stream>>>(deg, cnt_t, cntp, N);
    k_scan<<<1, 1024, 0, stream>>>(deg, rp, N, E);
    k_fill<<<(E + 255) / 256, 256, 0, stream>>>(ei, et, ep, rp, cursor, esrc, epack, E);
    k_gate<<<NPOS, HD, 0, stream>>>(pe, Wg, bg, gb);
    k_prep<<<(3 * 3 * HD * HD + 2 * HD * HD + 255) / 256, 256, 0, stream>>>(
        Wt, Wih, Whh, W1, WtT, Wihb, Whhb, W1T);
    k_init<<<(N * HD + 255) / 256, 256, 0, stream>>>(xidx, sel, emb, h, hbf0, N);

    const int gB32 = (N + 31) / 32;
    const short* hin = hbf0;
    short* hout = hbf1;
    for (int it = 0; it < GITERS; ++it) {
        k_iter<<<gB32, 1024, 0, stream>>>(rp, esrc, epack, hin, gb, WtT, bt, cntp,
                                          Wihb, Whhb, bih, bhh, h, hout, N);
        const short* tmp = hout;
        hout = (short*)hin;
        hin = tmp;
    }

    const int gB16 = (N + 15) / 16;
    k_final<<<gB16, 256, 0, stream>>>(hin, xidx, sel, emb, W1T, b1, W2, b2, (float*)d_out, N);
}

// Round 7
// 2104.398 us; speedup vs baseline: 1.6271x; 1.6271x over previous
//
#include <hip/hip_runtime.h>
#include <cstdint>
#include <cstddef>

#define HD 128
#define EMBD 96
#define SELD 32
#define PD 64
#define NPOS 513
#define GITERS 6

typedef _Float16 f16;
typedef __attribute__((ext_vector_type(8))) _Float16 f16x8;
typedef __attribute__((ext_vector_type(2))) _Float16 f16x2;
typedef __attribute__((ext_vector_type(4))) float f32x4;

__device__ __forceinline__ float sigm(float x) { return 1.0f / (1.0f + __expf(-x)); }

// ---------------- setup kernels ----------------

__global__ void k_deg(const int* __restrict__ ei, const int* __restrict__ et,
                      int* __restrict__ deg, int* __restrict__ cnt_t, int E, int N) {
    int e = blockIdx.x * 256 + threadIdx.x;
    if (e < E) {
        int d = ei[E + e];
        atomicAdd(&deg[d], 1);
        atomicAdd(&cnt_t[(size_t)et[e] * N + d], 1);
    }
}

__global__ void k_cntp(const int* __restrict__ deg, const int* __restrict__ cnt_t,
                       float4* __restrict__ cntp, int N) {
    int n = blockIdx.x * 256 + threadIdx.x;
    if (n < N) {
        float4 v;
        v.x = (float)cnt_t[n];
        v.y = (float)cnt_t[(size_t)N + n];
        v.z = (float)cnt_t[2 * (size_t)N + n];
        v.w = 1.0f / fmaxf((float)deg[n], 1.0f);
        cntp[n] = v;
    }
}

__launch_bounds__(1024)
__global__ void k_scan(const int* __restrict__ deg, int* __restrict__ rp, int N, int E) {
    __shared__ int sc[1024];
    int t = threadIdx.x;
    int chunk = (N + 1023) / 1024;
    int lo = t * chunk, hi = min(N, lo + chunk);
    int sum = 0;
    for (int i = lo; i < hi; ++i) sum += deg[i];
    sc[t] = sum;
    __syncthreads();
    for (int off = 1; off < 1024; off <<= 1) {
        int v = (t >= off) ? sc[t - off] : 0;
        __syncthreads();
        sc[t] += v;
        __syncthreads();
    }
    int base = sc[t] - sum;
    int run = base;
    for (int i = lo; i < hi; ++i) { rp[i] = run; run += deg[i]; }
    if (t == 1023) rp[N] = base + sum;
}

// epack: type<<10 | pos
__global__ void k_fill(const int* __restrict__ ei, const int* __restrict__ et,
                       const int* __restrict__ ep, const int* __restrict__ rp,
                       int* __restrict__ cursor, int* __restrict__ esrc,
                       int* __restrict__ epack, int E) {
    int e = blockIdx.x * 256 + threadIdx.x;
    if (e < E) {
        int d = ei[E + e];
        int pos = atomicAdd(&cursor[d], 1);
        int idx = rp[d] + pos;
        esrc[idx] = ei[e];
        epack[idx] = (et[e] << 10) | ep[e];
    }
}

__global__ void k_gate(const float* __restrict__ pe, const float* __restrict__ Wg,
                       const float* __restrict__ bg, f16* __restrict__ gb) {
    int p = blockIdx.x;
    int j = threadIdx.x;
    float acc = bg[j];
    #pragma unroll 8
    for (int k = 0; k < PD; ++k) acc += pe[p * PD + k] * Wg[k * HD + j];
    gb[p * HD + j] = (f16)(2.0f * sigm(acc));
}

// f16 weight prep (WtT transposed to [t][n][k]; Wih/Whh already B^T; W1T transposed)
__global__ void k_prep(const float* __restrict__ Wt, const float* __restrict__ Wih,
                       const float* __restrict__ Whh, const float* __restrict__ W1,
                       f16* __restrict__ WtT, f16* __restrict__ Wihb,
                       f16* __restrict__ Whhb, f16* __restrict__ W1T) {
    const int SZ = 3 * HD * HD;
    int id = blockIdx.x * 256 + threadIdx.x;
    if (id < SZ) {
        int t = id / (HD * HD), rem = id % (HD * HD);
        int n = rem / HD, k = rem % HD;
        WtT[id] = (f16)Wt[t * HD * HD + k * HD + n];
    } else if (id < 2 * SZ) {
        int i2 = id - SZ;
        Wihb[i2] = (f16)Wih[i2];
    } else if (id < 3 * SZ) {
        int i2 = id - 2 * SZ;
        Whhb[i2] = (f16)Whh[i2];
    } else if (id < 3 * SZ + 2 * HD * HD) {
        int rem = id - 3 * SZ;
        int n = rem / (2 * HD), k = rem % (2 * HD);
        W1T[rem] = (f16)W1[k * HD + n];
    }
}

__global__ void k_init(const int* __restrict__ xidx, const float* __restrict__ sel,
                       const float* __restrict__ emb, f16* __restrict__ h, int N) {
    int id = blockIdx.x * 256 + threadIdx.x;
    if (id < N * HD) {
        int n = id >> 7, j = id & 127;
        float v = (j < EMBD) ? emb[(size_t)xidx[n] * EMBD + j]
                             : sel[(size_t)n * SELD + (j - EMBD)];
        h[id] = (f16)v;
    }
}

// ---------------- fused per-iteration kernel ----------------
// 1024 threads = 16 waves, 16 dst rows per block. All state fp16, accum fp32.
// P1: wave w gathers row w's edges (masked batch-8, register accumulation)
//     -> per-type f16 sums S; own h row staged -> hL.
// P2: waves 0-7: agg MFMA + epilogue -> aggL.  waves 8-15: h@Whh -> ahL (f32).
// P3: waves 0-7: agg@Wih + combine + GRU epilogue (z*h from hL) -> hOut.
// P4: coalesced copy hOut -> h_out.
__launch_bounds__(1024, 8)
__global__ void k_iter(const int* __restrict__ rp, const int* __restrict__ esrc,
                       const int* __restrict__ epack, const f16* __restrict__ h_in,
                       const f16* __restrict__ gb, const f16* __restrict__ WtT,
                       const float* __restrict__ bt, const float4* __restrict__ cntp,
                       const f16* __restrict__ Wihb, const f16* __restrict__ Whhb,
                       const float* __restrict__ bih, const float* __restrict__ bhh,
                       f16* __restrict__ h_out, int N) {
    __shared__ f16 S[3 * 16 * 136];
    __shared__ f16 hL[16 * 136];
    __shared__ f16 aggL[16 * 136];
    __shared__ f16 hOut[16 * 136];
    __shared__ float ahL[8][3][64][4];

    int tid = threadIdx.x;
    int wave = tid >> 6, lane = tid & 63;
    int quad = lane >> 4, m = lane & 15;
    int d0 = blockIdx.x * 16;

    // ---- P1: stage own h row (wave w copies row w, lane l copies dword l)
    {
        int srow = min(d0 + wave, N - 1);
        uint32_t v = *(const uint32_t*)(h_in + (size_t)srow * HD + 2 * lane);
        *(uint32_t*)(hL + wave * 136 + 2 * lane) = v;
    }

    // ---- P1: gather, one dst row per wave, masked batch-8
    {
        int d = __builtin_amdgcn_readfirstlane(min(d0 + wave, N - 1));
        bool valid = (d0 + wave) < N;
        float a0x = 0.f, a0y = 0.f, a1x = 0.f, a1y = 0.f, a2x = 0.f, a2y = 0.f;
        int cl = 2 * lane;
        if (valid) {
            int es = rp[d], ee = rp[d + 1];
            for (int e = es; e < ee; e += 8) {
                #pragma unroll
                for (int j = 0; j < 8; ++j) {
                    int idx = min(e + j, ee - 1);
                    int sj = esrc[idx];
                    int pj = epack[idx];
                    f16x2 hv = *(const f16x2*)(h_in + (size_t)sj * HD + cl);
                    f16x2 gv = *(const f16x2*)(gb + (size_t)(pj & 1023) * HD + cl);
                    float mx = (float)hv[0] * (float)gv[0];
                    float my = (float)hv[1] * (float)gv[1];
                    if (e + j < ee) {  // wave-uniform predicate
                        int tt = (pj >> 10) & 3;
                        if (tt == 0)      { a0x += mx; a0y += my; }
                        else if (tt == 1) { a1x += mx; a1y += my; }
                        else              { a2x += mx; a2y += my; }
                    }
                }
            }
        }
        f16x2 w0 = {(f16)a0x, (f16)a0y};
        f16x2 w1 = {(f16)a1x, (f16)a1y};
        f16x2 w2 = {(f16)a2x, (f16)a2y};
        *(f16x2*)(S + (0 * 16 + wave) * 136 + cl) = w0;
        *(f16x2*)(S + (1 * 16 + wave) * 136 + cl) = w1;
        *(f16x2*)(S + (2 * 16 + wave) * 136 + cl) = w2;
    }
    __syncthreads();

    // ---- P2
    if (wave < 8) {
        int c0 = wave * 16;
        f32x4 acc = {0.f, 0.f, 0.f, 0.f};
        #pragma unroll
        for (int t = 0; t < 3; ++t)
            #pragma unroll
            for (int c = 0; c < 4; ++c) {
                f16x8 a = *(const f16x8*)(S + (t * 16 + m) * 136 + c * 32 + quad * 8);
                f16x8 b = *(const f16x8*)(WtT + ((size_t)t * HD + c0 + m) * HD + c * 32 + quad * 8);
                acc = __builtin_amdgcn_mfma_f32_16x16x32_f16(a, b, acc, 0, 0, 0);
            }
        int col = c0 + m;
        float bt0 = bt[col], bt1 = bt[HD + col], bt2 = bt[2 * HD + col];
        #pragma unroll
        for (int r = 0; r < 4; ++r) {
            int mm = quad * 4 + r;
            int dd = min(d0 + mm, N - 1);
            float4 cp = cntp[dd];
            float v = (acc[r] + cp.x * bt0 + cp.y * bt1 + cp.z * bt2) * cp.w;
            aggL[mm * 136 + col] = (f16)v;
        }
    } else {
        int sw = wave - 8;
        int c0 = sw * 16;
        f16x8 fh[4];
        #pragma unroll
        for (int c = 0; c < 4; ++c)
            fh[c] = *(const f16x8*)(hL + m * 136 + c * 32 + quad * 8);
        f32x4 ah[3];
        const f32x4 z4 = {0.f, 0.f, 0.f, 0.f};
        ah[0] = z4; ah[1] = z4; ah[2] = z4;
        #pragma unroll
        for (int g = 0; g < 3; ++g)
            #pragma unroll
            for (int c = 0; c < 4; ++c) {
                f16x8 b = *(const f16x8*)(Whhb + ((size_t)g * HD + c0 + m) * HD + c * 32 + quad * 8);
                ah[g] = __builtin_amdgcn_mfma_f32_16x16x32_f16(fh[c], b, ah[g], 0, 0, 0);
            }
        #pragma unroll
        for (int g = 0; g < 3; ++g)
            *(f32x4*)&ahL[sw][g][lane][0] = ah[g];
    }
    __syncthreads();

    // ---- P3: waves 0-7: agg @ Wih + combine + GRU epilogue
    if (wave < 8) {
        int c0 = wave * 16;
        f16x8 fa[4];
        #pragma unroll
        for (int c = 0; c < 4; ++c)
            fa[c] = *(const f16x8*)(aggL + m * 136 + c * 32 + quad * 8);
        f32x4 ai[3];
        const f32x4 z4 = {0.f, 0.f, 0.f, 0.f};
        ai[0] = z4; ai[1] = z4; ai[2] = z4;
        #pragma unroll
        for (int g = 0; g < 3; ++g)
            #pragma unroll
            for (int c = 0; c < 4; ++c) {
                f16x8 b = *(const f16x8*)(Wihb + ((size_t)g * HD + c0 + m) * HD + c * 32 + quad * 8);
                ai[g] = __builtin_amdgcn_mfma_f32_16x16x32_f16(fa[c], b, ai[g], 0, 0, 0);
            }
        f32x4 ah[3];
        #pragma unroll
        for (int g = 0; g < 3; ++g)
            ah[g] = *(const f32x4*)&ahL[wave][g][lane][0];

        int col = c0 + m;
        float bir = bih[col],          bhr = bhh[col];
        float biz = bih[HD + col],     bhz = bhh[HD + col];
        float bin = bih[2 * HD + col], bhn = bhh[2 * HD + col];
        #pragma unroll
        for (int r = 0; r < 4; ++r) {
            int row = quad * 4 + r;
            float rr = sigm(ai[0][r] + bir + ah[0][r] + bhr);
            float zz = sigm(ai[1][r] + biz + ah[1][r] + bhz);
            float nn = tanhf(ai[2][r] + bin + rr * (ah[2][r] + bhn));
            float hv = (float)hL[row * 136 + col];
            float hp = (1.0f - zz) * nn + zz * hv;
            hOut[row * 136 + col] = (f16)hp;
        }
    }
    __syncthreads();

    // ---- P4: coalesced copy hOut -> h_out (wave w copies row w)
    if (d0 + wave < N) {
        uint32_t v = *(const uint32_t*)(hOut + wave * 136 + 2 * lane);
        *(uint32_t*)(h_out + (size_t)(d0 + wave) * HD + 2 * lane) = v;
    }
}

// feats=[h|emb[x]|sel] (f16 frags) @ W1T (MFMA) -> relu -> @W2 + b2
__launch_bounds__(256)
__global__ void k_final(const f16* __restrict__ h_f, const int* __restrict__ xidx,
                        const float* __restrict__ sel, const float* __restrict__ emb,
                        const f16* __restrict__ W1T, const float* __restrict__ b1,
                        const float* __restrict__ W2, const float* __restrict__ b2,
                        float* __restrict__ out, int N) {
    __shared__ float red[4][16];
    int tid = threadIdx.x;
    int wave = tid >> 6, lane = tid & 63;
    int quad = lane >> 4, m = lane & 15;
    int row0 = blockIdx.x * 16;
    int arow = min(row0 + m, N - 1);
    int xi = xidx[arow];

    f16x8 fa[8];
    #pragma unroll
    for (int c = 0; c < 4; ++c)
        fa[c] = *(const f16x8*)(h_f + (size_t)arow * HD + c * 32 + quad * 8);
    #pragma unroll
    for (int c = 4; c < 7; ++c) {
        const float* ep = emb + (size_t)xi * EMBD + (c - 4) * 32 + quad * 8;
        #pragma unroll
        for (int j = 0; j < 8; ++j) fa[c][j] = (f16)ep[j];
    }
    {
        const float* sp = sel + (size_t)arow * SELD + quad * 8;
        #pragma unroll
        for (int j = 0; j < 8; ++j) fa[7][j] = (f16)sp[j];
    }

    f32x4 acc[2];
    const f32x4 z4 = {0.f, 0.f, 0.f, 0.f};
    acc[0] = z4; acc[1] = z4;
    #pragma unroll
    for (int s = 0; s < 2; ++s) {
        int c0 = (wave * 2 + s) * 16;
        #pragma unroll
        for (int c = 0; c < 8; ++c) {
            f16x8 b = *(const f16x8*)(W1T + (size_t)(c0 + m) * (2 * HD) + c * 32 + quad * 8);
            acc[s] = __builtin_amdgcn_mfma_f32_16x16x32_f16(fa[c], b, acc[s], 0, 0, 0);
        }
    }

    float psum[4] = {0.f, 0.f, 0.f, 0.f};
    #pragma unroll
    for (int s = 0; s < 2; ++s) {
        int col = (wave * 2 + s) * 16 + m;
        float b1v = b1[col], w2v = W2[col];
        #pragma unroll
        for (int r = 0; r < 4; ++r)
            psum[r] += fmaxf(acc[s][r] + b1v, 0.0f) * w2v;
    }
    #pragma unroll
    for (int off = 1; off < 16; off <<= 1)
        #pragma unroll
        for (int r = 0; r < 4; ++r) psum[r] += __shfl_xor(psum[r], off);

    if (m == 0) {
        #pragma unroll
        for (int r = 0; r < 4; ++r) red[wave][quad * 4 + r] = psum[r];
    }
    __syncthreads();
    if (tid < 16) {
        int row = row0 + tid;
        if (row < N) out[row] = red[0][tid] + red[1][tid] + red[2][tid] + red[3][tid] + b2[0];
    }
}

// ---------------- launcher ----------------

extern "C" void kernel_launch(void* const* d_in, const int* in_sizes, int n_in,
                              void* d_out, int out_size, void* d_ws, size_t ws_size,
                              hipStream_t stream) {
    const int*   xidx = (const int*)d_in[0];
    const float* sel  = (const float*)d_in[1];
    const int*   ei   = (const int*)d_in[2];
    const int*   et   = (const int*)d_in[3];
    const int*   ep   = (const int*)d_in[4];
    const float* emb  = (const float*)d_in[5];
    const float* pe   = (const float*)d_in[6];
    const float* Wg   = (const float*)d_in[7];
    const float* bg   = (const float*)d_in[8];
    const float* Wt   = (const float*)d_in[9];
    const float* bt   = (const float*)d_in[10];
    const float* Wih  = (const float*)d_in[11];
    const float* Whh  = (const float*)d_in[12];
    const float* bih  = (const float*)d_in[13];
    const float* bhh  = (const float*)d_in[14];
    const float* W1   = (const float*)d_in[15];
    const float* b1   = (const float*)d_in[16];
    const float* W2   = (const float*)d_in[17];
    const float* b2   = (const float*)d_in[18];

    const int N = in_sizes[0];
    const int E = in_sizes[3];
    const size_t NH = (size_t)N * HD;

    char* p = (char*)d_ws;
    f16*    hbf0  = (f16*)p;    p += NH * 2;
    f16*    hbf1  = (f16*)p;    p += NH * 2;
    f16*    gb    = (f16*)p;    p += (size_t)NPOS * HD * 2;
    f16*    WtT   = (f16*)p;    p += 3 * HD * HD * 2;
    f16*    Wihb  = (f16*)p;    p += 3 * HD * HD * 2;
    f16*    Whhb  = (f16*)p;    p += 3 * HD * HD * 2;
    f16*    W1T   = (f16*)p;    p += 2 * HD * HD * 2;
    float4* cntp  = (float4*)p; p += (size_t)N * 16;
    int* deg    = (int*)p; p += (size_t)N * 4;
    int* cnt_t  = (int*)p; p += 3 * (size_t)N * 4;
    int* rp     = (int*)p; p += (size_t)(N + 1) * 4;
    int* cursor = (int*)p; p += (size_t)N * 4;
    int* esrc   = (int*)p; p += (size_t)E * 4;
    int* epack  = (int*)p;

    // ---- setup ----
    hipMemsetAsync(deg, 0, (size_t)N * sizeof(int), stream);
    hipMemsetAsync(cnt_t, 0, 3 * (size_t)N * sizeof(int), stream);
    hipMemsetAsync(cursor, 0, (size_t)N * sizeof(int), stream);
    k_deg<<<(E + 255) / 256, 256, 0, stream>>>(ei, et, deg, cnt_t, E, N);
    k_cntp<<<(N + 255) / 256, 256, 0, stream>>>(deg, cnt_t, cntp, N);
    k_scan<<<1, 1024, 0, stream>>>(deg, rp, N, E);
    k_fill<<<(E + 255) / 256, 256, 0, stream>>>(ei, et, ep, rp, cursor, esrc, epack, E);
    k_gate<<<NPOS, HD, 0, stream>>>(pe, Wg, bg, gb);
    k_prep<<<(3 * 3 * HD * HD + 2 * HD * HD + 255) / 256, 256, 0, stream>>>(
        Wt, Wih, Whh, W1, WtT, Wihb, Whhb, W1T);
    k_init<<<(N * HD + 255) / 256, 256, 0, stream>>>(xidx, sel, emb, hbf0, N);

    const int gB = (N + 15) / 16;
    const f16* hin = hbf0;
    f16* hout = hbf1;
    for (int it = 0; it < GITERS; ++it) {
        k_iter<<<gB, 1024, 0, stream>>>(rp, esrc, epack, hin, gb, WtT, bt, cntp,
                                        Wihb, Whhb, bih, bhh, hout, N);
        const f16* tmp = hout;
        hout = (f16*)hin;
        hin = tmp;
    }

    k_final<<<gB, 256, 0, stream>>>(hin, xidx, sel, emb, W1T, b1, W2, b2, (float*)d_out, N);
}

// Round 8
// 1743.298 us; speedup vs baseline: 1.9641x; 1.2071x over previous
//
#include <hip/hip_runtime.h>
#include <cstdint>
#include <cstddef>

#define HD 128
#define EMBD 96
#define SELD 32
#define PD 64
#define NPOS 513
#define GITERS 6

typedef _Float16 f16;
typedef __attribute__((ext_vector_type(8))) _Float16 f16x8;
typedef __attribute__((ext_vector_type(4))) _Float16 f16x4;
typedef __attribute__((ext_vector_type(2))) _Float16 f16x2;
typedef __attribute__((ext_vector_type(4))) float f32x4;

__device__ __forceinline__ float sigm(float x) { return 1.0f / (1.0f + __expf(-x)); }

// ---------------- setup kernels ----------------

__global__ void k_deg(const int* __restrict__ ei, const int* __restrict__ et,
                      int* __restrict__ deg, int* __restrict__ cnt_t, int E, int N) {
    int e = blockIdx.x * 256 + threadIdx.x;
    if (e < E) {
        int d = ei[E + e];
        atomicAdd(&deg[d], 1);
        atomicAdd(&cnt_t[(size_t)et[e] * N + d], 1);
    }
}

__global__ void k_cntp(const int* __restrict__ deg, const int* __restrict__ cnt_t,
                       float4* __restrict__ cntp, int N) {
    int n = blockIdx.x * 256 + threadIdx.x;
    if (n < N) {
        float4 v;
        v.x = (float)cnt_t[n];
        v.y = (float)cnt_t[(size_t)N + n];
        v.z = (float)cnt_t[2 * (size_t)N + n];
        v.w = 1.0f / fmaxf((float)deg[n], 1.0f);
        cntp[n] = v;
    }
}

__launch_bounds__(1024)
__global__ void k_scan(const int* __restrict__ deg, int* __restrict__ rp, int N, int E) {
    __shared__ int sc[1024];
    int t = threadIdx.x;
    int chunk = (N + 1023) / 1024;
    int lo = t * chunk, hi = min(N, lo + chunk);
    int sum = 0;
    for (int i = lo; i < hi; ++i) sum += deg[i];
    sc[t] = sum;
    __syncthreads();
    for (int off = 1; off < 1024; off <<= 1) {
        int v = (t >= off) ? sc[t - off] : 0;
        __syncthreads();
        sc[t] += v;
        __syncthreads();
    }
    int base = sc[t] - sum;
    int run = base;
    for (int i = lo; i < hi; ++i) { rp[i] = run; run += deg[i]; }
    if (t == 1023) rp[N] = base + sum;
}

// epack: type<<10 | pos
__global__ void k_fill(const int* __restrict__ ei, const int* __restrict__ et,
                       const int* __restrict__ ep, const int* __restrict__ rp,
                       int* __restrict__ cursor, int* __restrict__ esrc,
                       int* __restrict__ epack, int E) {
    int e = blockIdx.x * 256 + threadIdx.x;
    if (e < E) {
        int d = ei[E + e];
        int pos = atomicAdd(&cursor[d], 1);
        int idx = rp[d] + pos;
        esrc[idx] = ei[e];
        epack[idx] = (et[e] << 10) | ep[e];
    }
}

__global__ void k_gate(const float* __restrict__ pe, const float* __restrict__ Wg,
                       const float* __restrict__ bg, f16* __restrict__ gb) {
    int p = blockIdx.x;
    int j = threadIdx.x;
    float acc = bg[j];
    #pragma unroll 8
    for (int k = 0; k < PD; ++k) acc += pe[p * PD + k] * Wg[k * HD + j];
    gb[p * HD + j] = (f16)(2.0f * sigm(acc));
}

// WtT[t][n][k] = Wt[t][k][n]; W1T[n][k] = W1[k][n]
__global__ void k_prep(const float* __restrict__ Wt, const float* __restrict__ W1,
                       f16* __restrict__ WtT, f16* __restrict__ W1T) {
    const int SZ = 3 * HD * HD;
    int id = blockIdx.x * 256 + threadIdx.x;
    if (id < SZ) {
        int t = id / (HD * HD), rem = id % (HD * HD);
        int n = rem / HD, k = rem % HD;
        WtT[id] = (f16)Wt[t * HD * HD + k * HD + n];
    } else if (id < SZ + 2 * HD * HD) {
        int rem = id - SZ;
        int n = rem / (2 * HD), k = rem % (2 * HD);
        W1T[rem] = (f16)W1[k * HD + n];
    }
}

// Wcat [512 rows j][256 k]:
//  j in [0,256):   [Wih[j] | Whh[j]]           (r rows then z rows, K fused)
//  j in [256,384): [Wih[j] | 0]                (i_n, K=0..127 used)
//  j in [384,512): [0 | Whh[j-128]]            (h_n, K=128..255 used)
__global__ void k_prepW(const float* __restrict__ Wih, const float* __restrict__ Whh,
                        f16* __restrict__ Wcat) {
    int id = blockIdx.x * 256 + threadIdx.x;
    if (id < 512 * 256) {
        int j = id >> 8, k = id & 255;
        float v;
        if (j < 256)      v = (k < 128) ? Wih[j * 128 + k] : Whh[j * 128 + (k - 128)];
        else if (j < 384) v = (k < 128) ? Wih[j * 128 + k] : 0.0f;
        else              v = (k < 128) ? 0.0f : Whh[(j - 128) * 128 + (k - 128)];
        Wcat[id] = (f16)v;
    }
}

__global__ void k_init(const int* __restrict__ xidx, const float* __restrict__ sel,
                       const float* __restrict__ emb, f16* __restrict__ h, int N) {
    int id = blockIdx.x * 256 + threadIdx.x;
    if (id < N * HD) {
        int n = id >> 7, j = id & 127;
        float v = (j < EMBD) ? emb[(size_t)xidx[n] * EMBD + j]
                             : sel[(size_t)n * SELD + (j - EMBD)];
        h[id] = (f16)v;
    }
}

// ---------------- per-iteration kernel A: gather + message matmul ----------------
// 32 rows/block, 1024 thr (16 waves). P1: wave w gathers rows w and 16+w.
// P2: wave w = (tau=w>>3, cg=w&7): 12 MFMAs, epilogue -> aggL -> coalesced agg.
__launch_bounds__(1024)
__global__ void k_agg(const int* __restrict__ rp, const int* __restrict__ esrc,
                      const int* __restrict__ epack, const f16* __restrict__ h_in,
                      const f16* __restrict__ gb, const f16* __restrict__ WtT,
                      const float* __restrict__ bt, const float4* __restrict__ cntp,
                      f16* __restrict__ agg, int N) {
    __shared__ f16 S[3 * 32 * 136];
    __shared__ f16 aggL[32 * 136];

    int tid = threadIdx.x;
    int wave = tid >> 6, lane = tid & 63;
    int quad = lane >> 4, m = lane & 15;
    int d0 = blockIdx.x * 32;
    int cl = 2 * lane;

    // ---- P1: gather two rows per wave (masked batch-8 each)
    #pragma unroll
    for (int rr = 0; rr < 2; ++rr) {
        int lrow = rr * 16 + wave;
        int d = __builtin_amdgcn_readfirstlane(min(d0 + lrow, N - 1));
        bool valid = (d0 + lrow) < N;
        float a0x = 0.f, a0y = 0.f, a1x = 0.f, a1y = 0.f, a2x = 0.f, a2y = 0.f;
        if (valid) {
            int es = rp[d], ee = rp[d + 1];
            for (int e = es; e < ee; e += 8) {
                #pragma unroll
                for (int j = 0; j < 8; ++j) {
                    int idx = min(e + j, ee - 1);
                    int sj = esrc[idx];
                    int pj = epack[idx];
                    f16x2 hv = *(const f16x2*)(h_in + (size_t)sj * HD + cl);
                    f16x2 gv = *(const f16x2*)(gb + (size_t)(pj & 1023) * HD + cl);
                    float mx = (float)hv[0] * (float)gv[0];
                    float my = (float)hv[1] * (float)gv[1];
                    if (e + j < ee) {  // wave-uniform predicate
                        int tt = (pj >> 10) & 3;
                        if (tt == 0)      { a0x += mx; a0y += my; }
                        else if (tt == 1) { a1x += mx; a1y += my; }
                        else              { a2x += mx; a2y += my; }
                    }
                }
            }
        }
        f16x2 w0 = {(f16)a0x, (f16)a0y};
        f16x2 w1 = {(f16)a1x, (f16)a1y};
        f16x2 w2 = {(f16)a2x, (f16)a2y};
        *(f16x2*)(S + (0 * 32 + lrow) * 136 + cl) = w0;
        *(f16x2*)(S + (1 * 32 + lrow) * 136 + cl) = w1;
        *(f16x2*)(S + (2 * 32 + lrow) * 136 + cl) = w2;
    }
    __syncthreads();

    // ---- P2: message matmul, wave = (tau, cg)
    {
        int tau = wave >> 3, cg = wave & 7;
        int col = cg * 16 + m;
        f32x4 acc = {0.f, 0.f, 0.f, 0.f};
        #pragma unroll
        for (int t = 0; t < 3; ++t)
            #pragma unroll
            for (int c = 0; c < 4; ++c) {
                f16x8 a = *(const f16x8*)(S + (t * 32 + tau * 16 + m) * 136 + c * 32 + quad * 8);
                f16x8 b = *(const f16x8*)(WtT + ((size_t)t * HD + col) * HD + c * 32 + quad * 8);
                acc = __builtin_amdgcn_mfma_f32_16x16x32_f16(a, b, acc, 0, 0, 0);
            }
        float bt0 = bt[col], bt1 = bt[HD + col], bt2 = bt[2 * HD + col];
        #pragma unroll
        for (int r = 0; r < 4; ++r) {
            int lr = tau * 16 + quad * 4 + r;
            int dd = min(d0 + lr, N - 1);
            float4 cp = cntp[dd];
            float v = (acc[r] + cp.x * bt0 + cp.y * bt1 + cp.z * bt2) * cp.w;
            aggL[lr * 136 + col] = (f16)v;
        }
    }
    __syncthreads();

    // ---- coalesced copy-out: thread t -> row t>>5, 4 elems at (t&31)*4
    {
        int row = tid >> 5, ch = tid & 31;
        if (d0 + row < N) {
            f16x4 v = *(const f16x4*)(aggL + row * 136 + ch * 4);
            *(f16x4*)(agg + (size_t)(d0 + row) * HD + ch * 4) = v;
        }
    }
}

// ---------------- per-iteration kernel B: GRU as 64-row GEMM ----------------
// A = [agg|h] (64x256, LDS), B = Wcat (global, L2-hot). Wave w owns out col
// block j = w*16+m for all 3 gates; 96 MFMAs/wave, B-frags read once.
__launch_bounds__(512, 2)
__global__ void k_gru(const f16* __restrict__ agg, const f16* __restrict__ h_in,
                      const f16* __restrict__ Wcat, const float* __restrict__ bih,
                      const float* __restrict__ bhh, f16* __restrict__ h_out, int N) {
    __shared__ f16 AL[64 * 264];  // A tile, stride 264 (bank-spread)

    int tid = threadIdx.x;
    int wave = tid >> 6, lane = tid & 63;
    int quad = lane >> 4, m = lane & 15;
    int d0 = blockIdx.x * 64;

    // ---- stage A = [agg | h]
    {
        int rsub = tid >> 5;   // 0..15
        int ch = tid & 31;     // 0..31
        #pragma unroll
        for (int i = 0; i < 4; ++i) {
            int row = i * 16 + rsub;
            int grow = min(d0 + row, N - 1);
            f16x8 v;
            if (ch < 16) v = *(const f16x8*)(agg + (size_t)grow * HD + ch * 8);
            else         v = *(const f16x8*)(h_in + (size_t)grow * HD + (ch - 16) * 8);
            *(f16x8*)(AL + row * 264 + ch * 8) = v;
        }
    }
    __syncthreads();

    // ---- preload A-frags for 4 row-tiles
    f16x8 fa[4][8];
    #pragma unroll
    for (int tau = 0; tau < 4; ++tau)
        #pragma unroll
        for (int c = 0; c < 8; ++c)
            fa[tau][c] = *(const f16x8*)(AL + (tau * 16 + m) * 264 + c * 32 + quad * 8);

    int j = wave * 16 + m;  // output column within each gate
    f32x4 ar[4], az[4], an[4], ah[4];
    const f32x4 z4 = {0.f, 0.f, 0.f, 0.f};
    #pragma unroll
    for (int tau = 0; tau < 4; ++tau) { ar[tau] = z4; az[tau] = z4; an[tau] = z4; ah[tau] = z4; }

    #pragma unroll
    for (int c = 0; c < 8; ++c) {
        f16x8 br = *(const f16x8*)(Wcat + (size_t)j * 256 + c * 32 + quad * 8);
        f16x8 bz = *(const f16x8*)(Wcat + (size_t)(128 + j) * 256 + c * 32 + quad * 8);
        f16x8 bn = (c < 4)
            ? *(const f16x8*)(Wcat + (size_t)(256 + j) * 256 + c * 32 + quad * 8)
            : *(const f16x8*)(Wcat + (size_t)(384 + j) * 256 + c * 32 + quad * 8);
        #pragma unroll
        for (int tau = 0; tau < 4; ++tau) {
            ar[tau] = __builtin_amdgcn_mfma_f32_16x16x32_f16(fa[tau][c], br, ar[tau], 0, 0, 0);
            az[tau] = __builtin_amdgcn_mfma_f32_16x16x32_f16(fa[tau][c], bz, az[tau], 0, 0, 0);
            if (c < 4) an[tau] = __builtin_amdgcn_mfma_f32_16x16x32_f16(fa[tau][c], bn, an[tau], 0, 0, 0);
            else       ah[tau] = __builtin_amdgcn_mfma_f32_16x16x32_f16(fa[tau][c], bn, ah[tau], 0, 0, 0);
        }
    }

    // ---- GRU epilogue
    float b_r  = bih[j] + bhh[j];
    float b_z  = bih[HD + j] + bhh[HD + j];
    float b_in = bih[2 * HD + j];
    float b_hn = bhh[2 * HD + j];
    float hp[4][4];
    #pragma unroll
    for (int tau = 0; tau < 4; ++tau)
        #pragma unroll
        for (int r = 0; r < 4; ++r) {
            int row = tau * 16 + quad * 4 + r;
            float hval = (float)AL[row * 264 + 128 + j];
            float rr = sigm(ar[tau][r] + b_r);
            float zz = sigm(az[tau][r] + b_z);
            float nn = tanhf(an[tau][r] + b_in + rr * (ah[tau][r] + b_hn));
            hp[tau][r] = (1.0f - zz) * nn + zz * hval;
        }
    __syncthreads();  // all AL reads done before reuse as output staging

    #pragma unroll
    for (int tau = 0; tau < 4; ++tau)
        #pragma unroll
        for (int r = 0; r < 4; ++r)
            AL[(tau * 16 + quad * 4 + r) * 132 + j] = (f16)hp[tau][r];
    __syncthreads();

    // ---- coalesced copy-out
    {
        int rsub = tid >> 5, ch = tid & 31;
        #pragma unroll
        for (int i = 0; i < 4; ++i) {
            int row = i * 16 + rsub;
            if (d0 + row < N) {
                f16x4 v = *(const f16x4*)(AL + row * 132 + ch * 4);
                *(f16x4*)(h_out + (size_t)(d0 + row) * HD + ch * 4) = v;
            }
        }
    }
}

// feats=[h|emb[x]|sel] (f16 frags) @ W1T (MFMA) -> relu -> @W2 + b2
__launch_bounds__(256)
__global__ void k_final(const f16* __restrict__ h_f, const int* __restrict__ xidx,
                        const float* __restrict__ sel, const float* __restrict__ emb,
                        const f16* __restrict__ W1T, const float* __restrict__ b1,
                        const float* __restrict__ W2, const float* __restrict__ b2,
                        float* __restrict__ out, int N) {
    __shared__ float red[4][16];
    int tid = threadIdx.x;
    int wave = tid >> 6, lane = tid & 63;
    int quad = lane >> 4, m = lane & 15;
    int row0 = blockIdx.x * 16;
    int arow = min(row0 + m, N - 1);
    int xi = xidx[arow];

    f16x8 fa[8];
    #pragma unroll
    for (int c = 0; c < 4; ++c)
        fa[c] = *(const f16x8*)(h_f + (size_t)arow * HD + c * 32 + quad * 8);
    #pragma unroll
    for (int c = 4; c < 7; ++c) {
        const float* ep = emb + (size_t)xi * EMBD + (c - 4) * 32 + quad * 8;
        #pragma unroll
        for (int jj = 0; jj < 8; ++jj) fa[c][jj] = (f16)ep[jj];
    }
    {
        const float* sp = sel + (size_t)arow * SELD + quad * 8;
        #pragma unroll
        for (int jj = 0; jj < 8; ++jj) fa[7][jj] = (f16)sp[jj];
    }

    f32x4 acc[2];
    const f32x4 z4 = {0.f, 0.f, 0.f, 0.f};
    acc[0] = z4; acc[1] = z4;
    #pragma unroll
    for (int s = 0; s < 2; ++s) {
        int c0 = (wave * 2 + s) * 16;
        #pragma unroll
        for (int c = 0; c < 8; ++c) {
            f16x8 b = *(const f16x8*)(W1T + (size_t)(c0 + m) * (2 * HD) + c * 32 + quad * 8);
            acc[s] = __builtin_amdgcn_mfma_f32_16x16x32_f16(fa[c], b, acc[s], 0, 0, 0);
        }
    }

    float psum[4] = {0.f, 0.f, 0.f, 0.f};
    #pragma unroll
    for (int s = 0; s < 2; ++s) {
        int col = (wave * 2 + s) * 16 + m;
        float b1v = b1[col], w2v = W2[col];
        #pragma unroll
        for (int r = 0; r < 4; ++r)
            psum[r] += fmaxf(acc[s][r] + b1v, 0.0f) * w2v;
    }
    #pragma unroll
    for (int off = 1; off < 16; off <<= 1)
        #pragma unroll
        for (int r = 0; r < 4; ++r) psum[r] += __shfl_xor(psum[r], off);

    if (m == 0) {
        #pragma unroll
        for (int r = 0; r < 4; ++r) red[wave][quad * 4 + r] = psum[r];
    }
    __syncthreads();
    if (tid < 16) {
        int row = row0 + tid;
        if (row < N) out[row] = red[0][tid] + red[1][tid] + red[2][tid] + red[3][tid] + b2[0];
    }
}

// ---------------- launcher ----------------

extern "C" void kernel_launch(void* const* d_in, const int* in_sizes, int n_in,
                              void* d_out, int out_size, void* d_ws, size_t ws_size,
                              hipStream_t stream) {
    const int*   xidx = (const int*)d_in[0];
    const float* sel  = (const float*)d_in[1];
    const int*   ei   = (const int*)d_in[2];
    const int*   et   = (const int*)d_in[3];
    const int*   ep   = (const int*)d_in[4];
    const float* emb  = (const float*)d_in[5];
    const float* pe   = (const float*)d_in[6];
    const float* Wg   = (const float*)d_in[7];
    const float* bg   = (const float*)d_in[8];
    const float* Wt   = (const float*)d_in[9];
    const float* bt   = (const float*)d_in[10];
    const float* Wih  = (const float*)d_in[11];
    const float* Whh  = (const float*)d_in[12];
    const float* bih  = (const float*)d_in[13];
    const float* bhh  = (const float*)d_in[14];
    const float* W1   = (const float*)d_in[15];
    const float* b1   = (const float*)d_in[16];
    const float* W2   = (const float*)d_in[17];
    const float* b2   = (const float*)d_in[18];

    const int N = in_sizes[0];
    const int E = in_sizes[3];
    const size_t NH = (size_t)N * HD;

    char* p = (char*)d_ws;
    f16*    hbf0  = (f16*)p;    p += NH * 2;
    f16*    hbf1  = (f16*)p;    p += NH * 2;
    f16*    aggb  = (f16*)p;    p += NH * 2;
    f16*    gb    = (f16*)p;    p += (size_t)NPOS * HD * 2;
    f16*    WtT   = (f16*)p;    p += 3 * HD * HD * 2;
    f16*    Wcat  = (f16*)p;    p += 512 * 256 * 2;
    f16*    W1T   = (f16*)p;    p += 2 * HD * HD * 2;
    float4* cntp  = (float4*)p; p += (size_t)N * 16;
    int* deg    = (int*)p; p += (size_t)N * 4;
    int* cnt_t  = (int*)p; p += 3 * (size_t)N * 4;
    int* rp     = (int*)p; p += (size_t)(N + 1) * 4;
    int* cursor = (int*)p; p += (size_t)N * 4;
    int* esrc   = (int*)p; p += (size_t)E * 4;
    int* epack  = (int*)p;

    // ---- setup ----
    hipMemsetAsync(deg, 0, (size_t)N * sizeof(int), stream);
    hipMemsetAsync(cnt_t, 0, 3 * (size_t)N * sizeof(int), stream);
    hipMemsetAsync(cursor, 0, (size_t)N * sizeof(int), stream);
    k_deg<<<(E + 255) / 256, 256, 0, stream>>>(ei, et, deg, cnt_t, E, N);
    k_cntp<<<(N + 255) / 256, 256, 0, stream>>>(deg, cnt_t, cntp, N);
    k_scan<<<1, 1024, 0, stream>>>(deg, rp, N, E);
    k_fill<<<(E + 255) / 256, 256, 0, stream>>>(ei, et, ep, rp, cursor, esrc, epack, E);
    k_gate<<<NPOS, HD, 0, stream>>>(pe, Wg, bg, gb);
    k_prep<<<(3 * HD * HD + 2 * HD * HD + 255) / 256, 256, 0, stream>>>(Wt, W1, WtT, W1T);
    k_prepW<<<512, 256, 0, stream>>>(Wih, Whh, Wcat);
    k_init<<<(N * HD + 255) / 256, 256, 0, stream>>>(xidx, sel, emb, hbf0, N);

    const int gA = (N + 31) / 32;
    const int gG = (N + 63) / 64;
    const f16* hin = hbf0;
    f16* hout = hbf1;
    for (int it = 0; it < GITERS; ++it) {
        k_agg<<<gA, 1024, 0, stream>>>(rp, esrc, epack, hin, gb, WtT, bt, cntp, aggb, N);
        k_gru<<<gG, 512, 0, stream>>>(aggb, hin, Wcat, bih, bhh, hout, N);
        const f16* tmp = hout;
        hout = (f16*)hin;
        hin = tmp;
    }

    const int gF = (N + 15) / 16;
    k_final<<<gF, 256, 0, stream>>>(hin, xidx, sel, emb, W1T, b1, W2, b2, (float*)d_out, N);
}

// Round 9
// 1599.813 us; speedup vs baseline: 2.1402x; 1.0897x over previous
//
#include <hip/hip_runtime.h>
#include <cstdint>
#include <cstddef>

#define HD 128
#define EMBD 96
#define SELD 32
#define PD 64
#define NPOS 513
#define GITERS 6

typedef _Float16 f16;
typedef __attribute__((ext_vector_type(8))) _Float16 f16x8;
typedef __attribute__((ext_vector_type(4))) _Float16 f16x4;
typedef __attribute__((ext_vector_type(2))) _Float16 f16x2;
typedef __attribute__((ext_vector_type(4))) float f32x4;

__device__ __forceinline__ float sigm(float x) { return 1.0f / (1.0f + __expf(-x)); }

// ---------------- setup kernels ----------------

__global__ void k_deg(const int* __restrict__ ei, const int* __restrict__ et,
                      int* __restrict__ deg, int* __restrict__ cnt_t, int E, int N) {
    int e = blockIdx.x * 256 + threadIdx.x;
    if (e < E) {
        int d = ei[E + e];
        atomicAdd(&deg[d], 1);
        atomicAdd(&cnt_t[(size_t)et[e] * N + d], 1);
    }
}

// hierarchical scan level 1: per-block exclusive scan of deg -> rp, block sums
__launch_bounds__(1024)
__global__ void k_scan1(const int* __restrict__ deg, int* __restrict__ rp,
                        int* __restrict__ bsum, int N) {
    __shared__ int sc[1024];
    int t = threadIdx.x;
    int i = blockIdx.x * 1024 + t;
    int v = (i < N) ? deg[i] : 0;
    sc[t] = v;
    __syncthreads();
    for (int off = 1; off < 1024; off <<= 1) {
        int u = (t >= off) ? sc[t - off] : 0;
        __syncthreads();
        sc[t] += u;
        __syncthreads();
    }
    if (i < N) rp[i] = sc[t] - v;  // exclusive within block
    if (t == 1023) bsum[blockIdx.x] = sc[t];
}

// level 2: exclusive scan of block sums (nb <= 1024), in place
__launch_bounds__(1024)
__global__ void k_scan2(int* __restrict__ bsum, int nb) {
    __shared__ int sc[1024];
    int t = threadIdx.x;
    int v = (t < nb) ? bsum[t] : 0;
    sc[t] = v;
    __syncthreads();
    for (int off = 1; off < 1024; off <<= 1) {
        int u = (t >= off) ? sc[t - off] : 0;
        __syncthreads();
        sc[t] += u;
        __syncthreads();
    }
    if (t < nb) bsum[t] = sc[t] - v;
}

// level 3: add block offsets (in place) + rp[N]=E + fused cntp build
__global__ void k_scan3(int* __restrict__ rp, const int* __restrict__ bsum,
                        const int* __restrict__ deg, const int* __restrict__ cnt_t,
                        float4* __restrict__ cntp, int N, int E) {
    int i = blockIdx.x * 256 + threadIdx.x;
    if (i < N) {
        rp[i] += bsum[i >> 10];
        float4 v;
        v.x = (float)cnt_t[i];
        v.y = (float)cnt_t[(size_t)N + i];
        v.z = (float)cnt_t[2 * (size_t)N + i];
        v.w = 1.0f / fmaxf((float)deg[i], 1.0f);
        cntp[i] = v;
    }
    if (i == 0) rp[N] = E;
}

// epack: type<<10 | pos
__global__ void k_fill(const int* __restrict__ ei, const int* __restrict__ et,
                       const int* __restrict__ ep, const int* __restrict__ rp,
                       int* __restrict__ cursor, int* __restrict__ esrc,
                       int* __restrict__ epack, int E) {
    int e = blockIdx.x * 256 + threadIdx.x;
    if (e < E) {
        int d = ei[E + e];
        int pos = atomicAdd(&cursor[d], 1);
        int idx = rp[d] + pos;
        esrc[idx] = ei[e];
        epack[idx] = (et[e] << 10) | ep[e];
    }
}

__global__ void k_gate(const float* __restrict__ pe, const float* __restrict__ Wg,
                       const float* __restrict__ bg, f16* __restrict__ gb) {
    int p = blockIdx.x;
    int j = threadIdx.x;
    float acc = bg[j];
    #pragma unroll 8
    for (int k = 0; k < PD; ++k) acc += pe[p * PD + k] * Wg[k * HD + j];
    gb[p * HD + j] = (f16)(2.0f * sigm(acc));
}

// WtT[t][n][k] = Wt[t][k][n]; W1T[n][k] = W1[k][n]
__global__ void k_prep(const float* __restrict__ Wt, const float* __restrict__ W1,
                       f16* __restrict__ WtT, f16* __restrict__ W1T) {
    const int SZ = 3 * HD * HD;
    int id = blockIdx.x * 256 + threadIdx.x;
    if (id < SZ) {
        int t = id / (HD * HD), rem = id % (HD * HD);
        int n = rem / HD, k = rem % HD;
        WtT[id] = (f16)Wt[t * HD * HD + k * HD + n];
    } else if (id < SZ + 2 * HD * HD) {
        int rem = id - SZ;
        int n = rem / (2 * HD), k = rem % (2 * HD);
        W1T[rem] = (f16)W1[k * HD + n];
    }
}

// Wcat [512 rows j][256 k]:
//  j in [0,256):   [Wih[j] | Whh[j]]           (r rows then z rows, K fused)
//  j in [256,384): [Wih[j] | 0]                (i_n)
//  j in [384,512): [0 | Whh[j-128]]            (h_n)
__global__ void k_prepW(const float* __restrict__ Wih, const float* __restrict__ Whh,
                        f16* __restrict__ Wcat) {
    int id = blockIdx.x * 256 + threadIdx.x;
    if (id < 512 * 256) {
        int j = id >> 8, k = id & 255;
        float v;
        if (j < 256)      v = (k < 128) ? Wih[j * 128 + k] : Whh[j * 128 + (k - 128)];
        else if (j < 384) v = (k < 128) ? Wih[j * 128 + k] : 0.0f;
        else              v = (k < 128) ? 0.0f : Whh[(j - 128) * 128 + (k - 128)];
        Wcat[id] = (f16)v;
    }
}

__global__ void k_init(const int* __restrict__ xidx, const float* __restrict__ sel,
                       const float* __restrict__ emb, f16* __restrict__ h, int N) {
    int id = blockIdx.x * 256 + threadIdx.x;
    if (id < N * HD) {
        int n = id >> 7, j = id & 127;
        float v = (j < EMBD) ? emb[(size_t)xidx[n] * EMBD + j]
                             : sel[(size_t)n * SELD + (j - EMBD)];
        h[id] = (f16)v;
    }
}

// ---------------- per-iteration kernel A: gather + message matmul ----------------
// 32 rows/block, 1024 thr (16 waves). P1: wave w gathers rows w and 16+w.
// P2: wave w = (tau=w>>3, cg=w&7): 12 MFMAs, epilogue -> aggL -> coalesced agg.
__launch_bounds__(1024)
__global__ void k_agg(const int* __restrict__ rp, const int* __restrict__ esrc,
                      const int* __restrict__ epack, const f16* __restrict__ h_in,
                      const f16* __restrict__ gb, const f16* __restrict__ WtT,
                      const float* __restrict__ bt, const float4* __restrict__ cntp,
                      f16* __restrict__ agg, int N) {
    __shared__ f16 S[3 * 32 * 136];
    __shared__ f16 aggL[32 * 136];

    int tid = threadIdx.x;
    int wave = tid >> 6, lane = tid & 63;
    int quad = lane >> 4, m = lane & 15;
    int d0 = blockIdx.x * 32;
    int cl = 2 * lane;

    // ---- P1: gather two rows per wave (masked batch-8 each)
    #pragma unroll
    for (int rr = 0; rr < 2; ++rr) {
        int lrow = rr * 16 + wave;
        int d = __builtin_amdgcn_readfirstlane(min(d0 + lrow, N - 1));
        bool valid = (d0 + lrow) < N;
        float a0x = 0.f, a0y = 0.f, a1x = 0.f, a1y = 0.f, a2x = 0.f, a2y = 0.f;
        if (valid) {
            int es = rp[d], ee = rp[d + 1];
            for (int e = es; e < ee; e += 8) {
                #pragma unroll
                for (int j = 0; j < 8; ++j) {
                    int idx = min(e + j, ee - 1);
                    int sj = esrc[idx];
                    int pj = epack[idx];
                    f16x2 hv = *(const f16x2*)(h_in + (size_t)sj * HD + cl);
                    f16x2 gv = *(const f16x2*)(gb + (size_t)(pj & 1023) * HD + cl);
                    float mx = (float)hv[0] * (float)gv[0];
                    float my = (float)hv[1] * (float)gv[1];
                    if (e + j < ee) {  // wave-uniform predicate
                        int tt = (pj >> 10) & 3;
                        if (tt == 0)      { a0x += mx; a0y += my; }
                        else if (tt == 1) { a1x += mx; a1y += my; }
                        else              { a2x += mx; a2y += my; }
                    }
                }
            }
        }
        f16x2 w0 = {(f16)a0x, (f16)a0y};
        f16x2 w1 = {(f16)a1x, (f16)a1y};
        f16x2 w2 = {(f16)a2x, (f16)a2y};
        *(f16x2*)(S + (0 * 32 + lrow) * 136 + cl) = w0;
        *(f16x2*)(S + (1 * 32 + lrow) * 136 + cl) = w1;
        *(f16x2*)(S + (2 * 32 + lrow) * 136 + cl) = w2;
    }
    __syncthreads();

    // ---- P2: message matmul, wave = (tau, cg)
    {
        int tau = wave >> 3, cg = wave & 7;
        int col = cg * 16 + m;
        f32x4 acc = {0.f, 0.f, 0.f, 0.f};
        #pragma unroll
        for (int t = 0; t < 3; ++t)
            #pragma unroll
            for (int c = 0; c < 4; ++c) {
                f16x8 a = *(const f16x8*)(S + (t * 32 + tau * 16 + m) * 136 + c * 32 + quad * 8);
                f16x8 b = *(const f16x8*)(WtT + ((size_t)t * HD + col) * HD + c * 32 + quad * 8);
                acc = __builtin_amdgcn_mfma_f32_16x16x32_f16(a, b, acc, 0, 0, 0);
            }
        float bt0 = bt[col], bt1 = bt[HD + col], bt2 = bt[2 * HD + col];
        #pragma unroll
        for (int r = 0; r < 4; ++r) {
            int lr = tau * 16 + quad * 4 + r;
            int dd = min(d0 + lr, N - 1);
            float4 cp = cntp[dd];
            float v = (acc[r] + cp.x * bt0 + cp.y * bt1 + cp.z * bt2) * cp.w;
            aggL[lr * 136 + col] = (f16)v;
        }
    }
    __syncthreads();

    // ---- coalesced copy-out: thread t -> row t>>5, 4 elems at (t&31)*4
    {
        int row = tid >> 5, ch = tid & 31;
        if (d0 + row < N) {
            f16x4 v = *(const f16x4*)(aggL + row * 136 + ch * 4);
            *(f16x4*)(agg + (size_t)(d0 + row) * HD + ch * 4) = v;
        }
    }
}

// ---------------- per-iteration kernel B: GRU as 64-row GEMM ----------------
// A = [agg|h] (64x256, LDS), B = Wcat (global, L2-hot). Wave w owns out col
// block j = w*16+m for all 3 gates; 96 MFMAs/wave, B-frags read once.
__launch_bounds__(512, 2)
__global__ void k_gru(const f16* __restrict__ agg, const f16* __restrict__ h_in,
                      const f16* __restrict__ Wcat, const float* __restrict__ bih,
                      const float* __restrict__ bhh, f16* __restrict__ h_out, int N) {
    __shared__ f16 AL[64 * 264];  // A tile, stride 264 (bank-spread)

    int tid = threadIdx.x;
    int wave = tid >> 6, lane = tid & 63;
    int quad = lane >> 4, m = lane & 15;
    int d0 = blockIdx.x * 64;

    // ---- stage A = [agg | h]
    {
        int rsub = tid >> 5;   // 0..15
        int ch = tid & 31;     // 0..31
        #pragma unroll
        for (int i = 0; i < 4; ++i) {
            int row = i * 16 + rsub;
            int grow = min(d0 + row, N - 1);
            f16x8 v;
            if (ch < 16) v = *(const f16x8*)(agg + (size_t)grow * HD + ch * 8);
            else         v = *(const f16x8*)(h_in + (size_t)grow * HD + (ch - 16) * 8);
            *(f16x8*)(AL + row * 264 + ch * 8) = v;
        }
    }
    __syncthreads();

    // ---- preload A-frags for 4 row-tiles
    f16x8 fa[4][8];
    #pragma unroll
    for (int tau = 0; tau < 4; ++tau)
        #pragma unroll
        for (int c = 0; c < 8; ++c)
            fa[tau][c] = *(const f16x8*)(AL + (tau * 16 + m) * 264 + c * 32 + quad * 8);

    int j = wave * 16 + m;  // output column within each gate
    f32x4 ar[4], az[4], an[4], ah[4];
    const f32x4 z4 = {0.f, 0.f, 0.f, 0.f};
    #pragma unroll
    for (int tau = 0; tau < 4; ++tau) { ar[tau] = z4; az[tau] = z4; an[tau] = z4; ah[tau] = z4; }

    #pragma unroll
    for (int c = 0; c < 8; ++c) {
        f16x8 br = *(const f16x8*)(Wcat + (size_t)j * 256 + c * 32 + quad * 8);
        f16x8 bz = *(const f16x8*)(Wcat + (size_t)(128 + j) * 256 + c * 32 + quad * 8);
        f16x8 bn = (c < 4)
            ? *(const f16x8*)(Wcat + (size_t)(256 + j) * 256 + c * 32 + quad * 8)
            : *(const f16x8*)(Wcat + (size_t)(384 + j) * 256 + c * 32 + quad * 8);
        #pragma unroll
        for (int tau = 0; tau < 4; ++tau) {
            ar[tau] = __builtin_amdgcn_mfma_f32_16x16x32_f16(fa[tau][c], br, ar[tau], 0, 0, 0);
            az[tau] = __builtin_amdgcn_mfma_f32_16x16x32_f16(fa[tau][c], bz, az[tau], 0, 0, 0);
            if (c < 4) an[tau] = __builtin_amdgcn_mfma_f32_16x16x32_f16(fa[tau][c], bn, an[tau], 0, 0, 0);
            else       ah[tau] = __builtin_amdgcn_mfma_f32_16x16x32_f16(fa[tau][c], bn, ah[tau], 0, 0, 0);
        }
    }

    // ---- GRU epilogue
    float b_r  = bih[j] + bhh[j];
    float b_z  = bih[HD + j] + bhh[HD + j];
    float b_in = bih[2 * HD + j];
    float b_hn = bhh[2 * HD + j];
    float hp[4][4];
    #pragma unroll
    for (int tau = 0; tau < 4; ++tau)
        #pragma unroll
        for (int r = 0; r < 4; ++r) {
            int row = tau * 16 + quad * 4 + r;
            float hval = (float)AL[row * 264 + 128 + j];
            float rr = sigm(ar[tau][r] + b_r);
            float zz = sigm(az[tau][r] + b_z);
            float nn = tanhf(an[tau][r] + b_in + rr * (ah[tau][r] + b_hn));
            hp[tau][r] = (1.0f - zz) * nn + zz * hval;
        }
    __syncthreads();  // all AL reads done before reuse as output staging

    #pragma unroll
    for (int tau = 0; tau < 4; ++tau)
        #pragma unroll
        for (int r = 0; r < 4; ++r)
            AL[(tau * 16 + quad * 4 + r) * 132 + j] = (f16)hp[tau][r];
    __syncthreads();

    // ---- coalesced copy-out
    {
        int rsub = tid >> 5, ch = tid & 31;
        #pragma unroll
        for (int i = 0; i < 4; ++i) {
            int row = i * 16 + rsub;
            if (d0 + row < N) {
                f16x4 v = *(const f16x4*)(AL + row * 132 + ch * 4);
                *(f16x4*)(h_out + (size_t)(d0 + row) * HD + ch * 4) = v;
            }
        }
    }
}

// feats=[h|emb[x]|sel] (f16 frags) @ W1T (MFMA) -> relu -> @W2 + b2
__launch_bounds__(256)
__global__ void k_final(const f16* __restrict__ h_f, const int* __restrict__ xidx,
                        const float* __restrict__ sel, const float* __restrict__ emb,
                        const f16* __restrict__ W1T, const float* __restrict__ b1,
                        const float* __restrict__ W2, const float* __restrict__ b2,
                        float* __restrict__ out, int N) {
    __shared__ float red[4][16];
    int tid = threadIdx.x;
    int wave = tid >> 6, lane = tid & 63;
    int quad = lane >> 4, m = lane & 15;
    int row0 = blockIdx.x * 16;
    int arow = min(row0 + m, N - 1);
    int xi = xidx[arow];

    f16x8 fa[8];
    #pragma unroll
    for (int c = 0; c < 4; ++c)
        fa[c] = *(const f16x8*)(h_f + (size_t)arow * HD + c * 32 + quad * 8);
    #pragma unroll
    for (int c = 4; c < 7; ++c) {
        const float* ep = emb + (size_t)xi * EMBD + (c - 4) * 32 + quad * 8;
        #pragma unroll
        for (int jj = 0; jj < 8; ++jj) fa[c][jj] = (f16)ep[jj];
    }
    {
        const float* sp = sel + (size_t)arow * SELD + quad * 8;
        #pragma unroll
        for (int jj = 0; jj < 8; ++jj) fa[7][jj] = (f16)sp[jj];
    }

    f32x4 acc[2];
    const f32x4 z4 = {0.f, 0.f, 0.f, 0.f};
    acc[0] = z4; acc[1] = z4;
    #pragma unroll
    for (int s = 0; s < 2; ++s) {
        int c0 = (wave * 2 + s) * 16;
        #pragma unroll
        for (int c = 0; c < 8; ++c) {
            f16x8 b = *(const f16x8*)(W1T + (size_t)(c0 + m) * (2 * HD) + c * 32 + quad * 8);
            acc[s] = __builtin_amdgcn_mfma_f32_16x16x32_f16(fa[c], b, acc[s], 0, 0, 0);
        }
    }

    float psum[4] = {0.f, 0.f, 0.f, 0.f};
    #pragma unroll
    for (int s = 0; s < 2; ++s) {
        int col = (wave * 2 + s) * 16 + m;
        float b1v = b1[col], w2v = W2[col];
        #pragma unroll
        for (int r = 0; r < 4; ++r)
            psum[r] += fmaxf(acc[s][r] + b1v, 0.0f) * w2v;
    }
    #pragma unroll
    for (int off = 1; off < 16; off <<= 1)
        #pragma unroll
        for (int r = 0; r < 4; ++r) psum[r] += __shfl_xor(psum[r], off);

    if (m == 0) {
        #pragma unroll
        for (int r = 0; r < 4; ++r) red[wave][quad * 4 + r] = psum[r];
    }
    __syncthreads();
    if (tid < 16) {
        int row = row0 + tid;
        if (row < N) out[row] = red[0][tid] + red[1][tid] + red[2][tid] + red[3][tid] + b2[0];
    }
}

// ---------------- launcher ----------------

extern "C" void kernel_launch(void* const* d_in, const int* in_sizes, int n_in,
                              void* d_out, int out_size, void* d_ws, size_t ws_size,
                              hipStream_t stream) {
    const int*   xidx = (const int*)d_in[0];
    const float* sel  = (const float*)d_in[1];
    const int*   ei   = (const int*)d_in[2];
    const int*   et   = (const int*)d_in[3];
    const int*   ep   = (const int*)d_in[4];
    const float* emb  = (const float*)d_in[5];
    const float* pe   = (const float*)d_in[6];
    const float* Wg   = (const float*)d_in[7];
    const float* bg   = (const float*)d_in[8];
    const float* Wt   = (const float*)d_in[9];
    const float* bt   = (const float*)d_in[10];
    const float* Wih  = (const float*)d_in[11];
    const float* Whh  = (const float*)d_in[12];
    const float* bih  = (const float*)d_in[13];
    const float* bhh  = (const float*)d_in[14];
    const float* W1   = (const float*)d_in[15];
    const float* b1   = (const float*)d_in[16];
    const float* W2   = (const float*)d_in[17];
    const float* b2   = (const float*)d_in[18];

    const int N = in_sizes[0];
    const int E = in_sizes[3];
    const size_t NH = (size_t)N * HD;

    char* p = (char*)d_ws;
    f16*    hbf0  = (f16*)p;    p += NH * 2;
    f16*    hbf1  = (f16*)p;    p += NH * 2;
    f16*    aggb  = (f16*)p;    p += NH * 2;
    f16*    gb    = (f16*)p;    p += (size_t)NPOS * HD * 2;
    f16*    WtT   = (f16*)p;    p += 3 * HD * HD * 2;
    f16*    Wcat  = (f16*)p;    p += 512 * 256 * 2;
    f16*    W1T   = (f16*)p;    p += 2 * HD * HD * 2;
    float4* cntp  = (float4*)p; p += (size_t)N * 16;
    int* deg    = (int*)p; p += (size_t)N * 4;
    int* cnt_t  = (int*)p; p += 3 * (size_t)N * 4;
    int* rp     = (int*)p; p += (size_t)(N + 1) * 4;
    int* cursor = (int*)p; p += (size_t)N * 4;
    int* bsum   = (int*)p; p += 1024 * 4;
    int* esrc   = (int*)p; p += (size_t)E * 4;
    int* epack  = (int*)p;

    // ---- setup ----
    hipMemsetAsync(deg, 0, (size_t)N * sizeof(int), stream);
    hipMemsetAsync(cnt_t, 0, 3 * (size_t)N * sizeof(int), stream);
    hipMemsetAsync(cursor, 0, (size_t)N * sizeof(int), stream);
    k_deg<<<(E + 255) / 256, 256, 0, stream>>>(ei, et, deg, cnt_t, E, N);
    const int nb1 = (N + 1023) / 1024;
    k_scan1<<<nb1, 1024, 0, stream>>>(deg, rp, bsum, N);
    k_scan2<<<1, 1024, 0, stream>>>(bsum, nb1);
    k_scan3<<<(N + 255) / 256, 256, 0, stream>>>(rp, bsum, deg, cnt_t, cntp, N, E);
    k_fill<<<(E + 255) / 256, 256, 0, stream>>>(ei, et, ep, rp, cursor, esrc, epack, E);
    k_gate<<<NPOS, HD, 0, stream>>>(pe, Wg, bg, gb);
    k_prep<<<(3 * HD * HD + 2 * HD * HD + 255) / 256, 256, 0, stream>>>(Wt, W1, WtT, W1T);
    k_prepW<<<512, 256, 0, stream>>>(Wih, Whh, Wcat);
    k_init<<<(N * HD + 255) / 256, 256, 0, stream>>>(xidx, sel, emb, hbf0, N);

    const int gA = (N + 31) / 32;
    const int gG = (N + 63) / 64;
    const f16* hin = hbf0;
    f16* hout = hbf1;
    for (int it = 0; it < GITERS; ++it) {
        k_agg<<<gA, 1024, 0, stream>>>(rp, esrc, epack, hin, gb, WtT, bt, cntp, aggb, N);
        k_gru<<<gG, 512, 0, stream>>>(aggb, hin, Wcat, bih, bhh, hout, N);
        const f16* tmp = hout;
        hout = (f16*)hin;
        hin = tmp;
    }

    const int gF = (N + 15) / 16;
    k_final<<<gF, 256, 0, stream>>>(hin, xidx, sel, emb, W1T, b1, W2, b2, (float*)d_out, N);
}

// Round 10
// 1532.319 us; speedup vs baseline: 2.2345x; 1.0440x over previous
//
#include <hip/hip_runtime.h>
#include <cstdint>
#include <cstddef>

#define HD 128
#define EMBD 96
#define SELD 32
#define PD 64
#define NPOS 513
#define GITERS 6

typedef _Float16 f16;
typedef __attribute__((ext_vector_type(8))) _Float16 f16x8;
typedef __attribute__((ext_vector_type(4))) _Float16 f16x4;
typedef __attribute__((ext_vector_type(2))) _Float16 f16x2;
typedef __attribute__((ext_vector_type(4))) float f32x4;

__device__ __forceinline__ float sigm(float x) { return 1.0f / (1.0f + __expf(-x)); }

// ---------------- setup kernels ----------------

__global__ void k_deg(const int* __restrict__ ei, const int* __restrict__ et,
                      int* __restrict__ deg, int* __restrict__ cnt_t, int E, int N) {
    int e = blockIdx.x * 256 + threadIdx.x;
    if (e < E) {
        int d = ei[E + e];
        atomicAdd(&deg[d], 1);
        atomicAdd(&cnt_t[(size_t)et[e] * N + d], 1);
    }
}

// hierarchical scan level 1: per-block exclusive scan of deg -> rp, block sums
__launch_bounds__(1024)
__global__ void k_scan1(const int* __restrict__ deg, int* __restrict__ rp,
                        int* __restrict__ bsum, int N) {
    __shared__ int sc[1024];
    int t = threadIdx.x;
    int i = blockIdx.x * 1024 + t;
    int v = (i < N) ? deg[i] : 0;
    sc[t] = v;
    __syncthreads();
    for (int off = 1; off < 1024; off <<= 1) {
        int u = (t >= off) ? sc[t - off] : 0;
        __syncthreads();
        sc[t] += u;
        __syncthreads();
    }
    if (i < N) rp[i] = sc[t] - v;  // exclusive within block
    if (t == 1023) bsum[blockIdx.x] = sc[t];
}

// level 2: exclusive scan of block sums (nb <= 1024), in place
__launch_bounds__(1024)
__global__ void k_scan2(int* __restrict__ bsum, int nb) {
    __shared__ int sc[1024];
    int t = threadIdx.x;
    int v = (t < nb) ? bsum[t] : 0;
    sc[t] = v;
    __syncthreads();
    for (int off = 1; off < 1024; off <<= 1) {
        int u = (t >= off) ? sc[t - off] : 0;
        __syncthreads();
        sc[t] += u;
        __syncthreads();
    }
    if (t < nb) bsum[t] = sc[t] - v;
}

// level 3: add block offsets (in place) + rp[N]=E + fused cntp build
__global__ void k_scan3(int* __restrict__ rp, const int* __restrict__ bsum,
                        const int* __restrict__ deg, const int* __restrict__ cnt_t,
                        float4* __restrict__ cntp, int N, int E) {
    int i = blockIdx.x * 256 + threadIdx.x;
    if (i < N) {
        rp[i] += bsum[i >> 10];
        float4 v;
        v.x = (float)cnt_t[i];
        v.y = (float)cnt_t[(size_t)N + i];
        v.z = (float)cnt_t[2 * (size_t)N + i];
        v.w = 1.0f / fmaxf((float)deg[i], 1.0f);
        cntp[i] = v;
    }
    if (i == 0) rp[N] = E;
}

// epack: type<<10 | pos
__global__ void k_fill(const int* __restrict__ ei, const int* __restrict__ et,
                       const int* __restrict__ ep, const int* __restrict__ rp,
                       int* __restrict__ cursor, int* __restrict__ esrc,
                       int* __restrict__ epack, int E) {
    int e = blockIdx.x * 256 + threadIdx.x;
    if (e < E) {
        int d = ei[E + e];
        int pos = atomicAdd(&cursor[d], 1);
        int idx = rp[d] + pos;
        esrc[idx] = ei[e];
        epack[idx] = (et[e] << 10) | ep[e];
    }
}

__global__ void k_gate(const float* __restrict__ pe, const float* __restrict__ Wg,
                       const float* __restrict__ bg, f16* __restrict__ gb) {
    int p = blockIdx.x;
    int j = threadIdx.x;
    float acc = bg[j];
    #pragma unroll 8
    for (int k = 0; k < PD; ++k) acc += pe[p * PD + k] * Wg[k * HD + j];
    gb[p * HD + j] = (f16)(2.0f * sigm(acc));
}

// WtT[t][n][k] = Wt[t][k][n]; W1T[n][k] = W1[k][n]
__global__ void k_prep(const float* __restrict__ Wt, const float* __restrict__ W1,
                       f16* __restrict__ WtT, f16* __restrict__ W1T) {
    const int SZ = 3 * HD * HD;
    int id = blockIdx.x * 256 + threadIdx.x;
    if (id < SZ) {
        int t = id / (HD * HD), rem = id % (HD * HD);
        int n = rem / HD, k = rem % HD;
        WtT[id] = (f16)Wt[t * HD * HD + k * HD + n];
    } else if (id < SZ + 2 * HD * HD) {
        int rem = id - SZ;
        int n = rem / (2 * HD), k = rem % (2 * HD);
        W1T[rem] = (f16)W1[k * HD + n];
    }
}

// Wcat [512 rows j][256 k]:
//  j in [0,256):   [Wih[j] | Whh[j]]           (r rows then z rows, K fused)
//  j in [256,384): [Wih[j] | 0]                (i_n)
//  j in [384,512): [0 | Whh[j-128]]            (h_n)
__global__ void k_prepW(const float* __restrict__ Wih, const float* __restrict__ Whh,
                        f16* __restrict__ Wcat) {
    int id = blockIdx.x * 256 + threadIdx.x;
    if (id < 512 * 256) {
        int j = id >> 8, k = id & 255;
        float v;
        if (j < 256)      v = (k < 128) ? Wih[j * 128 + k] : Whh[j * 128 + (k - 128)];
        else if (j < 384) v = (k < 128) ? Wih[j * 128 + k] : 0.0f;
        else              v = (k < 128) ? 0.0f : Whh[(j - 128) * 128 + (k - 128)];
        Wcat[id] = (f16)v;
    }
}

__global__ void k_init(const int* __restrict__ xidx, const float* __restrict__ sel,
                       const float* __restrict__ emb, f16* __restrict__ h, int N) {
    int id = blockIdx.x * 256 + threadIdx.x;
    if (id < N * HD) {
        int n = id >> 7, j = id & 127;
        float v = (j < EMBD) ? emb[(size_t)xidx[n] * EMBD + j]
                             : sel[(size_t)n * SELD + (j - EMBD)];
        h[id] = (f16)v;
    }
}

// ---------------- per-iteration kernel A: gather + message matmul ----------------
// 16 rows/block, 512 thr (8 waves). P1: wave w gathers rows w (lanes 0-31) and
// w+8 (lanes 32-63) SIMULTANEOUSLY — each half-wave covers a full 256B row with
// f16x4 per lane, so the two rows' load chains overlap instead of serializing.
// P2: wave w -> cols w*16..+15: 12 MFMAs, epilogue -> aggL -> coalesced agg.
__launch_bounds__(512, 4)
__global__ void k_agg(const int* __restrict__ rp, const int* __restrict__ esrc,
                      const int* __restrict__ epack, const f16* __restrict__ h_in,
                      const f16* __restrict__ gb, const f16* __restrict__ WtT,
                      const float* __restrict__ bt, const float4* __restrict__ cntp,
                      f16* __restrict__ agg, int N) {
    __shared__ f16 S[3 * 16 * 136];
    __shared__ f16 aggL[16 * 136];

    int tid = threadIdx.x;
    int wave = tid >> 6, lane = tid & 63;
    int quad = lane >> 4, m = lane & 15;
    int half = lane >> 5, hl = lane & 31;
    int d0 = blockIdx.x * 16;

    // ---- P1: dual-row gather
    {
        int lrow = wave + half * 8;
        int grow = d0 + lrow;
        bool valid = grow < N;
        int dd = min(grow, N - 1);
        int es = valid ? rp[dd] : 0;
        int ee = valid ? rp[dd + 1] : 0;
        int dg = ee - es;
        int dmax = max(dg, __shfl_xor(dg, 32));
        int nb = (__builtin_amdgcn_readfirstlane(dmax) + 7) >> 3;
        int co = hl * 4;  // 4 f16 cols per lane

        float a0[4] = {0.f, 0.f, 0.f, 0.f};
        float a1[4] = {0.f, 0.f, 0.f, 0.f};
        float a2[4] = {0.f, 0.f, 0.f, 0.f};
        for (int b = 0; b < nb; ++b) {
            int e0 = es + b * 8;
            int pj[8];
            f16x4 hv[8], gv[8];
            #pragma unroll
            for (int j = 0; j < 8; ++j) {
                int idx = max(min(e0 + j, ee - 1), 0);
                int sj = esrc[idx];
                pj[j] = epack[idx];
                hv[j] = *(const f16x4*)(h_in + (size_t)sj * HD + co);
                gv[j] = *(const f16x4*)(gb + (size_t)(pj[j] & 1023) * HD + co);
            }
            #pragma unroll
            for (int j = 0; j < 8; ++j) {
                bool act = (e0 + j) < ee;
                int tt = (pj[j] >> 10) & 3;
                #pragma unroll
                for (int q = 0; q < 4; ++q) {
                    float mv = (float)hv[j][q] * (float)gv[j][q];
                    mv = act ? mv : 0.0f;
                    a0[q] += (tt == 0) ? mv : 0.0f;
                    a1[q] += (tt == 1) ? mv : 0.0f;
                    a2[q] += (tt == 2) ? mv : 0.0f;
                }
            }
        }
        f16x4 s0 = {(f16)a0[0], (f16)a0[1], (f16)a0[2], (f16)a0[3]};
        f16x4 s1 = {(f16)a1[0], (f16)a1[1], (f16)a1[2], (f16)a1[3]};
        f16x4 s2 = {(f16)a2[0], (f16)a2[1], (f16)a2[2], (f16)a2[3]};
        *(f16x4*)(S + (0 * 16 + lrow) * 136 + co) = s0;
        *(f16x4*)(S + (1 * 16 + lrow) * 136 + co) = s1;
        *(f16x4*)(S + (2 * 16 + lrow) * 136 + co) = s2;
    }
    __syncthreads();

    // ---- P2: message matmul: wave w -> cols w*16..+15
    {
        int col = wave * 16 + m;
        f32x4 acc = {0.f, 0.f, 0.f, 0.f};
        #pragma unroll
        for (int t = 0; t < 3; ++t)
            #pragma unroll
            for (int c = 0; c < 4; ++c) {
                f16x8 a = *(const f16x8*)(S + (t * 16 + m) * 136 + c * 32 + quad * 8);
                f16x8 b = *(const f16x8*)(WtT + ((size_t)t * HD + col) * HD + c * 32 + quad * 8);
                acc = __builtin_amdgcn_mfma_f32_16x16x32_f16(a, b, acc, 0, 0, 0);
            }
        float bt0 = bt[col], bt1 = bt[HD + col], bt2 = bt[2 * HD + col];
        #pragma unroll
        for (int r = 0; r < 4; ++r) {
            int lr = quad * 4 + r;
            int dd2 = min(d0 + lr, N - 1);
            float4 cp = cntp[dd2];
            float v = (acc[r] + cp.x * bt0 + cp.y * bt1 + cp.z * bt2) * cp.w;
            aggL[lr * 136 + col] = (f16)v;
        }
    }
    __syncthreads();

    // ---- coalesced copy-out: thread t -> row t>>5, 4 f16 at (t&31)*4
    {
        int row = tid >> 5, ch = tid & 31;
        if (d0 + row < N) {
            f16x4 v = *(const f16x4*)(aggL + row * 136 + ch * 4);
            *(f16x4*)(agg + (size_t)(d0 + row) * HD + ch * 4) = v;
        }
    }
}

// ---------------- per-iteration kernel B: GRU as 64-row GEMM ----------------
// A = [agg|h] (64x256, LDS), B = Wcat (global, L2-hot). Wave w owns out col
// block j = w*16+m for all 3 gates; 96 MFMAs/wave, B-frags read once.
__launch_bounds__(512, 2)
__global__ void k_gru(const f16* __restrict__ agg, const f16* __restrict__ h_in,
                      const f16* __restrict__ Wcat, const float* __restrict__ bih,
                      const float* __restrict__ bhh, f16* __restrict__ h_out, int N) {
    __shared__ f16 AL[64 * 264];  // A tile, stride 264 (bank-spread)

    int tid = threadIdx.x;
    int wave = tid >> 6, lane = tid & 63;
    int quad = lane >> 4, m = lane & 15;
    int d0 = blockIdx.x * 64;

    // ---- stage A = [agg | h]
    {
        int rsub = tid >> 5;   // 0..15
        int ch = tid & 31;     // 0..31
        #pragma unroll
        for (int i = 0; i < 4; ++i) {
            int row = i * 16 + rsub;
            int grow = min(d0 + row, N - 1);
            f16x8 v;
            if (ch < 16) v = *(const f16x8*)(agg + (size_t)grow * HD + ch * 8);
            else         v = *(const f16x8*)(h_in + (size_t)grow * HD + (ch - 16) * 8);
            *(f16x8*)(AL + row * 264 + ch * 8) = v;
        }
    }
    __syncthreads();

    // ---- preload A-frags for 4 row-tiles
    f16x8 fa[4][8];
    #pragma unroll
    for (int tau = 0; tau < 4; ++tau)
        #pragma unroll
        for (int c = 0; c < 8; ++c)
            fa[tau][c] = *(const f16x8*)(AL + (tau * 16 + m) * 264 + c * 32 + quad * 8);

    int j = wave * 16 + m;  // output column within each gate
    f32x4 ar[4], az[4], an[4], ah[4];
    const f32x4 z4 = {0.f, 0.f, 0.f, 0.f};
    #pragma unroll
    for (int tau = 0; tau < 4; ++tau) { ar[tau] = z4; az[tau] = z4; an[tau] = z4; ah[tau] = z4; }

    #pragma unroll
    for (int c = 0; c < 8; ++c) {
        f16x8 br = *(const f16x8*)(Wcat + (size_t)j * 256 + c * 32 + quad * 8);
        f16x8 bz = *(const f16x8*)(Wcat + (size_t)(128 + j) * 256 + c * 32 + quad * 8);
        f16x8 bn = (c < 4)
            ? *(const f16x8*)(Wcat + (size_t)(256 + j) * 256 + c * 32 + quad * 8)
            : *(const f16x8*)(Wcat + (size_t)(384 + j) * 256 + c * 32 + quad * 8);
        #pragma unroll
        for (int tau = 0; tau < 4; ++tau) {
            ar[tau] = __builtin_amdgcn_mfma_f32_16x16x32_f16(fa[tau][c], br, ar[tau], 0, 0, 0);
            az[tau] = __builtin_amdgcn_mfma_f32_16x16x32_f16(fa[tau][c], bz, az[tau], 0, 0, 0);
            if (c < 4) an[tau] = __builtin_amdgcn_mfma_f32_16x16x32_f16(fa[tau][c], bn, an[tau], 0, 0, 0);
            else       ah[tau] = __builtin_amdgcn_mfma_f32_16x16x32_f16(fa[tau][c], bn, ah[tau], 0, 0, 0);
        }
    }

    // ---- GRU epilogue
    float b_r  = bih[j] + bhh[j];
    float b_z  = bih[HD + j] + bhh[HD + j];
    float b_in = bih[2 * HD + j];
    float b_hn = bhh[2 * HD + j];
    float hp[4][4];
    #pragma unroll
    for (int tau = 0; tau < 4; ++tau)
        #pragma unroll
        for (int r = 0; r < 4; ++r) {
            int row = tau * 16 + quad * 4 + r;
            float hval = (float)AL[row * 264 + 128 + j];
            float rr = sigm(ar[tau][r] + b_r);
            float zz = sigm(az[tau][r] + b_z);
            float nn = tanhf(an[tau][r] + b_in + rr * (ah[tau][r] + b_hn));
            hp[tau][r] = (1.0f - zz) * nn + zz * hval;
        }
    __syncthreads();  // all AL reads done before reuse as output staging

    #pragma unroll
    for (int tau = 0; tau < 4; ++tau)
        #pragma unroll
        for (int r = 0; r < 4; ++r)
            AL[(tau * 16 + quad * 4 + r) * 132 + j] = (f16)hp[tau][r];
    __syncthreads();

    // ---- coalesced copy-out
    {
        int rsub = tid >> 5, ch = tid & 31;
        #pragma unroll
        for (int i = 0; i < 4; ++i) {
            int row = i * 16 + rsub;
            if (d0 + row < N) {
                f16x4 v = *(const f16x4*)(AL + row * 132 + ch * 4);
                *(f16x4*)(h_out + (size_t)(d0 + row) * HD + ch * 4) = v;
            }
        }
    }
}

// feats=[h|emb[x]|sel] (f16 frags) @ W1T (MFMA) -> relu -> @W2 + b2
__launch_bounds__(256)
__global__ void k_final(const f16* __restrict__ h_f, const int* __restrict__ xidx,
                        const float* __restrict__ sel, const float* __restrict__ emb,
                        const f16* __restrict__ W1T, const float* __restrict__ b1,
                        const float* __restrict__ W2, const float* __restrict__ b2,
                        float* __restrict__ out, int N) {
    __shared__ float red[4][16];
    int tid = threadIdx.x;
    int wave = tid >> 6, lane = tid & 63;
    int quad = lane >> 4, m = lane & 15;
    int row0 = blockIdx.x * 16;
    int arow = min(row0 + m, N - 1);
    int xi = xidx[arow];

    f16x8 fa[8];
    #pragma unroll
    for (int c = 0; c < 4; ++c)
        fa[c] = *(const f16x8*)(h_f + (size_t)arow * HD + c * 32 + quad * 8);
    #pragma unroll
    for (int c = 4; c < 7; ++c) {
        const float* ep = emb + (size_t)xi * EMBD + (c - 4) * 32 + quad * 8;
        #pragma unroll
        for (int jj = 0; jj < 8; ++jj) fa[c][jj] = (f16)ep[jj];
    }
    {
        const float* sp = sel + (size_t)arow * SELD + quad * 8;
        #pragma unroll
        for (int jj = 0; jj < 8; ++jj) fa[7][jj] = (f16)sp[jj];
    }

    f32x4 acc[2];
    const f32x4 z4 = {0.f, 0.f, 0.f, 0.f};
    acc[0] = z4; acc[1] = z4;
    #pragma unroll
    for (int s = 0; s < 2; ++s) {
        int c0 = (wave * 2 + s) * 16;
        #pragma unroll
        for (int c = 0; c < 8; ++c) {
            f16x8 b = *(const f16x8*)(W1T + (size_t)(c0 + m) * (2 * HD) + c * 32 + quad * 8);
            acc[s] = __builtin_amdgcn_mfma_f32_16x16x32_f16(fa[c], b, acc[s], 0, 0, 0);
        }
    }

    float psum[4] = {0.f, 0.f, 0.f, 0.f};
    #pragma unroll
    for (int s = 0; s < 2; ++s) {
        int col = (wave * 2 + s) * 16 + m;
        float b1v = b1[col], w2v = W2[col];
        #pragma unroll
        for (int r = 0; r < 4; ++r)
            psum[r] += fmaxf(acc[s][r] + b1v, 0.0f) * w2v;
    }
    #pragma unroll
    for (int off = 1; off < 16; off <<= 1)
        #pragma unroll
        for (int r = 0; r < 4; ++r) psum[r] += __shfl_xor(psum[r], off);

    if (m == 0) {
        #pragma unroll
        for (int r = 0; r < 4; ++r) red[wave][quad * 4 + r] = psum[r];
    }
    __syncthreads();
    if (tid < 16) {
        int row = row0 + tid;
        if (row < N) out[row] = red[0][tid] + red[1][tid] + red[2][tid] + red[3][tid] + b2[0];
    }
}

// ---------------- launcher ----------------

extern "C" void kernel_launch(void* const* d_in, const int* in_sizes, int n_in,
                              void* d_out, int out_size, void* d_ws, size_t ws_size,
                              hipStream_t stream) {
    const int*   xidx = (const int*)d_in[0];
    const float* sel  = (const float*)d_in[1];
    const int*   ei   = (const int*)d_in[2];
    const int*   et   = (const int*)d_in[3];
    const int*   ep   = (const int*)d_in[4];
    const float* emb  = (const float*)d_in[5];
    const float* pe   = (const float*)d_in[6];
    const float* Wg   = (const float*)d_in[7];
    const float* bg   = (const float*)d_in[8];
    const float* Wt   = (const float*)d_in[9];
    const float* bt   = (const float*)d_in[10];
    const float* Wih  = (const float*)d_in[11];
    const float* Whh  = (const float*)d_in[12];
    const float* bih  = (const float*)d_in[13];
    const float* bhh  = (const float*)d_in[14];
    const float* W1   = (const float*)d_in[15];
    const float* b1   = (const float*)d_in[16];
    const float* W2   = (const float*)d_in[17];
    const float* b2   = (const float*)d_in[18];

    const int N = in_sizes[0];
    const int E = in_sizes[3];
    const size_t NH = (size_t)N * HD;

    char* p = (char*)d_ws;
    f16*    hbf0  = (f16*)p;    p += NH * 2;
    f16*    hbf1  = (f16*)p;    p += NH * 2;
    f16*    aggb  = (f16*)p;    p += NH * 2;
    f16*    gb    = (f16*)p;    p += (size_t)NPOS * HD * 2;
    f16*    WtT   = (f16*)p;    p += 3 * HD * HD * 2;
    f16*    Wcat  = (f16*)p;    p += 512 * 256 * 2;
    f16*    W1T   = (f16*)p;    p += 2 * HD * HD * 2;
    float4* cntp  = (float4*)p; p += (size_t)N * 16;
    int* deg    = (int*)p; p += (size_t)N * 4;
    int* cnt_t  = (int*)p; p += 3 * (size_t)N * 4;
    int* rp     = (int*)p; p += (size_t)(N + 1) * 4;
    int* cursor = (int*)p; p += (size_t)N * 4;
    int* bsum   = (int*)p; p += 1024 * 4;
    int* esrc   = (int*)p; p += (size_t)E * 4;
    int* epack  = (int*)p;

    // ---- setup ----
    hipMemsetAsync(deg, 0, (size_t)N * sizeof(int), stream);
    hipMemsetAsync(cnt_t, 0, 3 * (size_t)N * sizeof(int), stream);
    hipMemsetAsync(cursor, 0, (size_t)N * sizeof(int), stream);
    k_deg<<<(E + 255) / 256, 256, 0, stream>>>(ei, et, deg, cnt_t, E, N);
    const int nb1 = (N + 1023) / 1024;
    k_scan1<<<nb1, 1024, 0, stream>>>(deg, rp, bsum, N);
    k_scan2<<<1, 1024, 0, stream>>>(bsum, nb1);
    k_scan3<<<(N + 255) / 256, 256, 0, stream>>>(rp, bsum, deg, cnt_t, cntp, N, E);
    k_fill<<<(E + 255) / 256, 256, 0, stream>>>(ei, et, ep, rp, cursor, esrc, epack, E);
    k_gate<<<NPOS, HD, 0, stream>>>(pe, Wg, bg, gb);
    k_prep<<<(3 * HD * HD + 2 * HD * HD + 255) / 256, 256, 0, stream>>>(Wt, W1, WtT, W1T);
    k_prepW<<<512, 256, 0, stream>>>(Wih, Whh, Wcat);
    k_init<<<(N * HD + 255) / 256, 256, 0, stream>>>(xidx, sel, emb, hbf0, N);

    const int gA = (N + 15) / 16;
    const int gG = (N + 63) / 64;
    const f16* hin = hbf0;
    f16* hout = hbf1;
    for (int it = 0; it < GITERS; ++it) {
        k_agg<<<gA, 512, 0, stream>>>(rp, esrc, epack, hin, gb, WtT, bt, cntp, aggb, N);
        k_gru<<<gG, 512, 0, stream>>>(aggb, hin, Wcat, bih, bhh, hout, N);
        const f16* tmp = hout;
        hout = (f16*)hin;
        hin = tmp;
    }

    const int gF = (N + 15) / 16;
    k_final<<<gF, 256, 0, stream>>>(hin, xidx, sel, emb, W1T, b1, W2, b2, (float*)d_out, N);
}

// Round 11
// 1509.330 us; speedup vs baseline: 2.2686x; 1.0152x over previous
//
#include <hip/hip_runtime.h>
#include <cstdint>
#include <cstddef>

#define HD 128
#define EMBD 96
#define SELD 32
#define PD 64
#define NPOS 513
#define GITERS 6

typedef _Float16 f16;
typedef __attribute__((ext_vector_type(8))) _Float16 f16x8;
typedef __attribute__((ext_vector_type(4))) _Float16 f16x4;
typedef __attribute__((ext_vector_type(2))) _Float16 f16x2;
typedef __attribute__((ext_vector_type(4))) float f32x4;

__device__ __forceinline__ float sigm(float x) { return 1.0f / (1.0f + __expf(-x)); }

// ---------------- setup kernels ----------------

__global__ void k_deg(const int* __restrict__ ei, const int* __restrict__ et,
                      int* __restrict__ deg, int* __restrict__ cnt_t, int E, int N) {
    int e = blockIdx.x * 256 + threadIdx.x;
    if (e < E) {
        int d = ei[E + e];
        atomicAdd(&deg[d], 1);
        atomicAdd(&cnt_t[(size_t)et[e] * N + d], 1);
    }
}

// hierarchical scan level 1: per-block exclusive scan of deg -> rp, block sums
__launch_bounds__(1024)
__global__ void k_scan1(const int* __restrict__ deg, int* __restrict__ rp,
                        int* __restrict__ bsum, int N) {
    __shared__ int sc[1024];
    int t = threadIdx.x;
    int i = blockIdx.x * 1024 + t;
    int v = (i < N) ? deg[i] : 0;
    sc[t] = v;
    __syncthreads();
    for (int off = 1; off < 1024; off <<= 1) {
        int u = (t >= off) ? sc[t - off] : 0;
        __syncthreads();
        sc[t] += u;
        __syncthreads();
    }
    if (i < N) rp[i] = sc[t] - v;  // exclusive within block
    if (t == 1023) bsum[blockIdx.x] = sc[t];
}

// level 2: exclusive scan of block sums (nb <= 1024), in place
__launch_bounds__(1024)
__global__ void k_scan2(int* __restrict__ bsum, int nb) {
    __shared__ int sc[1024];
    int t = threadIdx.x;
    int v = (t < nb) ? bsum[t] : 0;
    sc[t] = v;
    __syncthreads();
    for (int off = 1; off < 1024; off <<= 1) {
        int u = (t >= off) ? sc[t - off] : 0;
        __syncthreads();
        sc[t] += u;
        __syncthreads();
    }
    if (t < nb) bsum[t] = sc[t] - v;
}

// level 3: rp4[d] = (start, start+c0, start+c0+c1, end) + cntp build
__global__ void k_scan3(const int* __restrict__ rp, const int* __restrict__ bsum,
                        const int* __restrict__ cnt_t, float4* __restrict__ cntp,
                        int4* __restrict__ rp4, int N) {
    int i = blockIdx.x * 256 + threadIdx.x;
    if (i < N) {
        int start = rp[i] + bsum[i >> 10];
        int c0 = cnt_t[i];
        int c1 = cnt_t[(size_t)N + i];
        int c2 = cnt_t[2 * (size_t)N + i];
        rp4[i] = make_int4(start, start + c0, start + c0 + c1, start + c0 + c1 + c2);
        float4 v;
        v.x = (float)c0; v.y = (float)c1; v.z = (float)c2;
        v.w = 1.0f / fmaxf((float)(c0 + c1 + c2), 1.0f);
        cntp[i] = v;
    }
}

// type-sorted CSR fill: e2[slot] = (src, pos), slot = start + typebase + cursor
__global__ void k_fill(const int* __restrict__ ei, const int* __restrict__ et,
                       const int* __restrict__ ep, const int4* __restrict__ rp4,
                       const int* __restrict__ cnt_t, int* __restrict__ cur3,
                       int2* __restrict__ e2, int E, int N) {
    int e = blockIdx.x * 256 + threadIdx.x;
    if (e < E) {
        int d = ei[E + e];
        int t = et[e];
        int base = rp4[d].x;
        if (t > 0) base += cnt_t[d];
        if (t > 1) base += cnt_t[(size_t)N + d];
        int pos = atomicAdd(&cur3[(size_t)t * N + d], 1);
        e2[base + pos] = make_int2(ei[e], ep[e]);
    }
}

__global__ void k_gate(const float* __restrict__ pe, const float* __restrict__ Wg,
                       const float* __restrict__ bg, f16* __restrict__ gb) {
    int p = blockIdx.x;
    int j = threadIdx.x;
    float acc = bg[j];
    #pragma unroll 8
    for (int k = 0; k < PD; ++k) acc += pe[p * PD + k] * Wg[k * HD + j];
    gb[p * HD + j] = (f16)(2.0f * sigm(acc));
}

// WtT[t][n][k] = Wt[t][k][n]; W1T[n][k] = W1[k][n]
__global__ void k_prep(const float* __restrict__ Wt, const float* __restrict__ W1,
                       f16* __restrict__ WtT, f16* __restrict__ W1T) {
    const int SZ = 3 * HD * HD;
    int id = blockIdx.x * 256 + threadIdx.x;
    if (id < SZ) {
        int t = id / (HD * HD), rem = id % (HD * HD);
        int n = rem / HD, k = rem % HD;
        WtT[id] = (f16)Wt[t * HD * HD + k * HD + n];
    } else if (id < SZ + 2 * HD * HD) {
        int rem = id - SZ;
        int n = rem / (2 * HD), k = rem % (2 * HD);
        W1T[rem] = (f16)W1[k * HD + n];
    }
}

// Wcat [512 rows j][256 k]
__global__ void k_prepW(const float* __restrict__ Wih, const float* __restrict__ Whh,
                        f16* __restrict__ Wcat) {
    int id = blockIdx.x * 256 + threadIdx.x;
    if (id < 512 * 256) {
        int j = id >> 8, k = id & 255;
        float v;
        if (j < 256)      v = (k < 128) ? Wih[j * 128 + k] : Whh[j * 128 + (k - 128)];
        else if (j < 384) v = (k < 128) ? Wih[j * 128 + k] : 0.0f;
        else              v = (k < 128) ? 0.0f : Whh[(j - 128) * 128 + (k - 128)];
        Wcat[id] = (f16)v;
    }
}

__global__ void k_init(const int* __restrict__ xidx, const float* __restrict__ sel,
                       const float* __restrict__ emb, f16* __restrict__ h, int N) {
    int id = blockIdx.x * 256 + threadIdx.x;
    if (id < N * HD) {
        int n = id >> 7, j = id & 127;
        float v = (j < EMBD) ? emb[(size_t)xidx[n] * EMBD + j]
                             : sel[(size_t)n * SELD + (j - EMBD)];
        h[id] = (f16)v;
    }
}

// ---------------- per-iteration kernel A: gather + message matmul ----------------
// 16 rows/block, 512 thr (8 waves); wave w gathers rows w (lanes 0-31) and w+8
// (lanes 32-63) simultaneously. Type-sorted CSR + prefix-subtract accumulation
// in packed f16 (no per-edge type predication tree, no cvt ops).
__launch_bounds__(512, 4)
__global__ void k_agg(const int4* __restrict__ rp4, const int2* __restrict__ e2,
                      const f16* __restrict__ h_in, const f16* __restrict__ gb,
                      const f16* __restrict__ WtT, const float* __restrict__ bt,
                      const float4* __restrict__ cntp, f16* __restrict__ agg, int N) {
    __shared__ f16 S[3 * 16 * 136];
    __shared__ f16 aggL[16 * 136];

    int tid = threadIdx.x;
    int wave = tid >> 6, lane = tid & 63;
    int quad = lane >> 4, m = lane & 15;
    int half = lane >> 5, hl = lane & 31;
    int d0 = blockIdx.x * 16;

    // ---- P1: dual-row gather
    {
        int lrow = wave + half * 8;
        int grow = d0 + lrow;
        bool valid = grow < N;
        int4 r4 = rp4[min(grow, N - 1)];
        int es = r4.x, b1 = r4.y, b2 = r4.z, ee = r4.w;
        if (!valid) ee = es;
        int dg = ee - es;
        int dmax = max(dg, __shfl_xor(dg, 32));
        int nb = (__builtin_amdgcn_readfirstlane(dmax) + 7) >> 3;
        int co = hl * 4;  // 4 f16 cols per lane

        const f16x4 zf = {0, 0, 0, 0};
        f16x4 accA = zf, accB = zf, accC = zf;
        for (int b = 0; b < nb; ++b) {
            int e0 = es + b * 8;
            int2 ev[8];
            #pragma unroll
            for (int j = 0; j < 8; ++j) {
                int idx = max(min(e0 + j, ee - 1), 0);
                ev[j] = e2[idx];
            }
            f16x4 hv[8], gv[8];
            #pragma unroll
            for (int j = 0; j < 8; ++j) {
                hv[j] = *(const f16x4*)(h_in + (size_t)ev[j].x * HD + co);
                gv[j] = *(const f16x4*)(gb + (size_t)ev[j].y * HD + co);
            }
            #pragma unroll
            for (int j = 0; j < 8; ++j) {
                int eidx = e0 + j;
                f16x4 g0 = (eidx < ee) ? gv[j] : zf;   // active mask
                accA += hv[j] * g0;                     // v_pk_fma x2
                f16x4 gB = (eidx >= b1) ? g0 : zf;
                accB += hv[j] * gB;
                f16x4 gC = (eidx >= b2) ? g0 : zf;
                accC += hv[j] * gC;
            }
        }
        f16x4 s0 = accA - accB;   // type-0 sum
        f16x4 s1 = accB - accC;   // type-1 sum
        *(f16x4*)(S + (0 * 16 + lrow) * 136 + co) = s0;
        *(f16x4*)(S + (1 * 16 + lrow) * 136 + co) = s1;
        *(f16x4*)(S + (2 * 16 + lrow) * 136 + co) = accC;
    }
    __syncthreads();

    // ---- P2: message matmul: wave w -> cols w*16..+15
    {
        int col = wave * 16 + m;
        f32x4 acc = {0.f, 0.f, 0.f, 0.f};
        #pragma unroll
        for (int t = 0; t < 3; ++t)
            #pragma unroll
            for (int c = 0; c < 4; ++c) {
                f16x8 a = *(const f16x8*)(S + (t * 16 + m) * 136 + c * 32 + quad * 8);
                f16x8 b = *(const f16x8*)(WtT + ((size_t)t * HD + col) * HD + c * 32 + quad * 8);
                acc = __builtin_amdgcn_mfma_f32_16x16x32_f16(a, b, acc, 0, 0, 0);
            }
        float bt0 = bt[col], bt1 = bt[HD + col], bt2 = bt[2 * HD + col];
        #pragma unroll
        for (int r = 0; r < 4; ++r) {
            int lr = quad * 4 + r;
            int dd2 = min(d0 + lr, N - 1);
            float4 cp = cntp[dd2];
            float v = (acc[r] + cp.x * bt0 + cp.y * bt1 + cp.z * bt2) * cp.w;
            aggL[lr * 136 + col] = (f16)v;
        }
    }
    __syncthreads();

    // ---- coalesced copy-out: thread t -> row t>>5, 4 f16 at (t&31)*4
    {
        int row = tid >> 5, ch = tid & 31;
        if (d0 + row < N) {
            f16x4 v = *(const f16x4*)(aggL + row * 136 + ch * 4);
            *(f16x4*)(agg + (size_t)(d0 + row) * HD + ch * 4) = v;
        }
    }
}

// ---------------- per-iteration kernel B: GRU as 64-row GEMM ----------------
__launch_bounds__(512, 2)
__global__ void k_gru(const f16* __restrict__ agg, const f16* __restrict__ h_in,
                      const f16* __restrict__ Wcat, const float* __restrict__ bih,
                      const float* __restrict__ bhh, f16* __restrict__ h_out, int N) {
    __shared__ f16 AL[64 * 264];  // A tile, stride 264 (bank-spread)

    int tid = threadIdx.x;
    int wave = tid >> 6, lane = tid & 63;
    int quad = lane >> 4, m = lane & 15;
    int d0 = blockIdx.x * 64;

    // ---- stage A = [agg | h]
    {
        int rsub = tid >> 5;   // 0..15
        int ch = tid & 31;     // 0..31
        #pragma unroll
        for (int i = 0; i < 4; ++i) {
            int row = i * 16 + rsub;
            int grow = min(d0 + row, N - 1);
            f16x8 v;
            if (ch < 16) v = *(const f16x8*)(agg + (size_t)grow * HD + ch * 8);
            else         v = *(const f16x8*)(h_in + (size_t)grow * HD + (ch - 16) * 8);
            *(f16x8*)(AL + row * 264 + ch * 8) = v;
        }
    }
    __syncthreads();

    // ---- preload A-frags for 4 row-tiles
    f16x8 fa[4][8];
    #pragma unroll
    for (int tau = 0; tau < 4; ++tau)
        #pragma unroll
        for (int c = 0; c < 8; ++c)
            fa[tau][c] = *(const f16x8*)(AL + (tau * 16 + m) * 264 + c * 32 + quad * 8);

    int j = wave * 16 + m;  // output column within each gate
    f32x4 ar[4], az[4], an[4], ah[4];
    const f32x4 z4 = {0.f, 0.f, 0.f, 0.f};
    #pragma unroll
    for (int tau = 0; tau < 4; ++tau) { ar[tau] = z4; az[tau] = z4; an[tau] = z4; ah[tau] = z4; }

    #pragma unroll
    for (int c = 0; c < 8; ++c) {
        f16x8 br = *(const f16x8*)(Wcat + (size_t)j * 256 + c * 32 + quad * 8);
        f16x8 bz = *(const f16x8*)(Wcat + (size_t)(128 + j) * 256 + c * 32 + quad * 8);
        f16x8 bn = (c < 4)
            ? *(const f16x8*)(Wcat + (size_t)(256 + j) * 256 + c * 32 + quad * 8)
            : *(const f16x8*)(Wcat + (size_t)(384 + j) * 256 + c * 32 + quad * 8);
        #pragma unroll
        for (int tau = 0; tau < 4; ++tau) {
            ar[tau] = __builtin_amdgcn_mfma_f32_16x16x32_f16(fa[tau][c], br, ar[tau], 0, 0, 0);
            az[tau] = __builtin_amdgcn_mfma_f32_16x16x32_f16(fa[tau][c], bz, az[tau], 0, 0, 0);
            if (c < 4) an[tau] = __builtin_amdgcn_mfma_f32_16x16x32_f16(fa[tau][c], bn, an[tau], 0, 0, 0);
            else       ah[tau] = __builtin_amdgcn_mfma_f32_16x16x32_f16(fa[tau][c], bn, ah[tau], 0, 0, 0);
        }
    }

    // ---- GRU epilogue
    float b_r  = bih[j] + bhh[j];
    float b_z  = bih[HD + j] + bhh[HD + j];
    float b_in = bih[2 * HD + j];
    float b_hn = bhh[2 * HD + j];
    float hp[4][4];
    #pragma unroll
    for (int tau = 0; tau < 4; ++tau)
        #pragma unroll
        for (int r = 0; r < 4; ++r) {
            int row = tau * 16 + quad * 4 + r;
            float hval = (float)AL[row * 264 + 128 + j];
            float rr = sigm(ar[tau][r] + b_r);
            float zz = sigm(az[tau][r] + b_z);
            float nn = tanhf(an[tau][r] + b_in + rr * (ah[tau][r] + b_hn));
            hp[tau][r] = (1.0f - zz) * nn + zz * hval;
        }
    __syncthreads();  // all AL reads done before reuse as output staging

    #pragma unroll
    for (int tau = 0; tau < 4; ++tau)
        #pragma unroll
        for (int r = 0; r < 4; ++r)
            AL[(tau * 16 + quad * 4 + r) * 132 + j] = (f16)hp[tau][r];
    __syncthreads();

    // ---- coalesced copy-out
    {
        int rsub = tid >> 5, ch = tid & 31;
        #pragma unroll
        for (int i = 0; i < 4; ++i) {
            int row = i * 16 + rsub;
            if (d0 + row < N) {
                f16x4 v = *(const f16x4*)(AL + row * 132 + ch * 4);
                *(f16x4*)(h_out + (size_t)(d0 + row) * HD + ch * 4) = v;
            }
        }
    }
}

// feats=[h|emb[x]|sel] (f16 frags) @ W1T (MFMA) -> relu -> @W2 + b2
__launch_bounds__(256)
__global__ void k_final(const f16* __restrict__ h_f, const int* __restrict__ xidx,
                        const float* __restrict__ sel, const float* __restrict__ emb,
                        const f16* __restrict__ W1T, const float* __restrict__ b1,
                        const float* __restrict__ W2, const float* __restrict__ b2,
                        float* __restrict__ out, int N) {
    __shared__ float red[4][16];
    int tid = threadIdx.x;
    int wave = tid >> 6, lane = tid & 63;
    int quad = lane >> 4, m = lane & 15;
    int row0 = blockIdx.x * 16;
    int arow = min(row0 + m, N - 1);
    int xi = xidx[arow];

    f16x8 fa[8];
    #pragma unroll
    for (int c = 0; c < 4; ++c)
        fa[c] = *(const f16x8*)(h_f + (size_t)arow * HD + c * 32 + quad * 8);
    #pragma unroll
    for (int c = 4; c < 7; ++c) {
        const float* ep = emb + (size_t)xi * EMBD + (c - 4) * 32 + quad * 8;
        #pragma unroll
        for (int jj = 0; jj < 8; ++jj) fa[c][jj] = (f16)ep[jj];
    }
    {
        const float* sp = sel + (size_t)arow * SELD + quad * 8;
        #pragma unroll
        for (int jj = 0; jj < 8; ++jj) fa[7][jj] = (f16)sp[jj];
    }

    f32x4 acc[2];
    const f32x4 z4 = {0.f, 0.f, 0.f, 0.f};
    acc[0] = z4; acc[1] = z4;
    #pragma unroll
    for (int s = 0; s < 2; ++s) {
        int c0 = (wave * 2 + s) * 16;
        #pragma unroll
        for (int c = 0; c < 8; ++c) {
            f16x8 b = *(const f16x8*)(W1T + (size_t)(c0 + m) * (2 * HD) + c * 32 + quad * 8);
            acc[s] = __builtin_amdgcn_mfma_f32_16x16x32_f16(fa[c], b, acc[s], 0, 0, 0);
        }
    }

    float psum[4] = {0.f, 0.f, 0.f, 0.f};
    #pragma unroll
    for (int s = 0; s < 2; ++s) {
        int col = (wave * 2 + s) * 16 + m;
        float b1v = b1[col], w2v = W2[col];
        #pragma unroll
        for (int r = 0; r < 4; ++r)
            psum[r] += fmaxf(acc[s][r] + b1v, 0.0f) * w2v;
    }
    #pragma unroll
    for (int off = 1; off < 16; off <<= 1)
        #pragma unroll
        for (int r = 0; r < 4; ++r) psum[r] += __shfl_xor(psum[r], off);

    if (m == 0) {
        #pragma unroll
        for (int r = 0; r < 4; ++r) red[wave][quad * 4 + r] = psum[r];
    }
    __syncthreads();
    if (tid < 16) {
        int row = row0 + tid;
        if (row < N) out[row] = red[0][tid] + red[1][tid] + red[2][tid] + red[3][tid] + b2[0];
    }
}

// ---------------- launcher ----------------

extern "C" void kernel_launch(void* const* d_in, const int* in_sizes, int n_in,
                              void* d_out, int out_size, void* d_ws, size_t ws_size,
                              hipStream_t stream) {
    const int*   xidx = (const int*)d_in[0];
    const float* sel  = (const float*)d_in[1];
    const int*   ei   = (const int*)d_in[2];
    const int*   et   = (const int*)d_in[3];
    const int*   ep   = (const int*)d_in[4];
    const float* emb  = (const float*)d_in[5];
    const float* pe   = (const float*)d_in[6];
    const float* Wg   = (const float*)d_in[7];
    const float* bg   = (const float*)d_in[8];
    const float* Wt   = (const float*)d_in[9];
    const float* bt   = (const float*)d_in[10];
    const float* Wih  = (const float*)d_in[11];
    const float* Whh  = (const float*)d_in[12];
    const float* bih  = (const float*)d_in[13];
    const float* bhh  = (const float*)d_in[14];
    const float* W1   = (const float*)d_in[15];
    const float* b1   = (const float*)d_in[16];
    const float* W2   = (const float*)d_in[17];
    const float* b2   = (const float*)d_in[18];

    const int N = in_sizes[0];
    const int E = in_sizes[3];
    const size_t NH = (size_t)N * HD;

    char* p = (char*)d_ws;
    f16*    hbf0  = (f16*)p;    p += NH * 2;
    f16*    hbf1  = (f16*)p;    p += NH * 2;
    f16*    aggb  = (f16*)p;    p += NH * 2;
    f16*    gb    = (f16*)p;    p += (size_t)NPOS * HD * 2;
    f16*    WtT   = (f16*)p;    p += 3 * HD * HD * 2;
    f16*    Wcat  = (f16*)p;    p += 512 * 256 * 2;
    f16*    W1T   = (f16*)p;    p += 2 * HD * HD * 2;
    float4* cntp  = (float4*)p; p += (size_t)N * 16;
    int4*   rp4   = (int4*)p;   p += (size_t)N * 16;
    int* deg    = (int*)p; p += (size_t)N * 4;
    int* cnt_t  = (int*)p; p += 3 * (size_t)N * 4;
    int* rp     = (int*)p; p += (size_t)N * 4;
    int* cur3   = (int*)p; p += 3 * (size_t)N * 4;
    int* bsum   = (int*)p; p += 1024 * 4;
    int2* e2    = (int2*)p;

    // ---- setup ----
    hipMemsetAsync(deg, 0, (size_t)N * sizeof(int), stream);
    hipMemsetAsync(cnt_t, 0, 3 * (size_t)N * sizeof(int), stream);
    hipMemsetAsync(cur3, 0, 3 * (size_t)N * sizeof(int), stream);
    k_deg<<<(E + 255) / 256, 256, 0, stream>>>(ei, et, deg, cnt_t, E, N);
    const int nb1 = (N + 1023) / 1024;
    k_scan1<<<nb1, 1024, 0, stream>>>(deg, rp, bsum, N);
    k_scan2<<<1, 1024, 0, stream>>>(bsum, nb1);
    k_scan3<<<(N + 255) / 256, 256, 0, stream>>>(rp, bsum, cnt_t, cntp, rp4, N);
    k_fill<<<(E + 255) / 256, 256, 0, stream>>>(ei, et, ep, rp4, cnt_t, cur3, e2, E, N);
    k_gate<<<NPOS, HD, 0, stream>>>(pe, Wg, bg, gb);
    k_prep<<<(3 * HD * HD + 2 * HD * HD + 255) / 256, 256, 0, stream>>>(Wt, W1, WtT, W1T);
    k_prepW<<<512, 256, 0, stream>>>(Wih, Whh, Wcat);
    k_init<<<(N * HD + 255) / 256, 256, 0, stream>>>(xidx, sel, emb, hbf0, N);

    const int gA = (N + 15) / 16;
    const int gG = (N + 63) / 64;
    const f16* hin = hbf0;
    f16* hout = hbf1;
    for (int it = 0; it < GITERS; ++it) {
        k_agg<<<gA, 512, 0, stream>>>(rp4, e2, hin, gb, WtT, bt, cntp, aggb, N);
        k_gru<<<gG, 512, 0, stream>>>(aggb, hin, Wcat, bih, bhh, hout, N);
        const f16* tmp = hout;
        hout = (f16*)hin;
        hin = tmp;
    }

    const int gF = (N + 15) / 16;
    k_final<<<gF, 256, 0, stream>>>(hin, xidx, sel, emb, W1T, b1, W2, b2, (float*)d_out, N);
}

// Round 12
// 1353.051 us; speedup vs baseline: 2.5306x; 1.1155x over previous
//
#include <hip/hip_runtime.h>
#include <cstdint>
#include <cstddef>

#define HD 128
#define EMBD 96
#define SELD 32
#define PD 64
#define NPOS 513
#define GITERS 6

typedef _Float16 f16;
typedef __attribute__((ext_vector_type(8))) _Float16 f16x8;
typedef __attribute__((ext_vector_type(4))) _Float16 f16x4;
typedef __attribute__((ext_vector_type(2))) _Float16 f16x2;
typedef __attribute__((ext_vector_type(4))) float f32x4;

__device__ __forceinline__ float sigm(float x) {
    return __builtin_amdgcn_rcpf(1.0f + __expf(-x));
}
__device__ __forceinline__ float tanh_f(float x) {
    return 2.0f * __builtin_amdgcn_rcpf(1.0f + __expf(-2.0f * x)) - 1.0f;
}

// ---------------- setup kernels ----------------

// per-(type,dst) counts only (deg derived later)
__global__ void k_deg(const int* __restrict__ ei, const int* __restrict__ et,
                      int* __restrict__ cnt_t, int E, int N) {
    int e = blockIdx.x * 256 + threadIdx.x;
    if (e < E) {
        int d = ei[E + e];
        atomicAdd(&cnt_t[(size_t)et[e] * N + d], 1);
    }
}

// scan level 1: per-block exclusive scan of deg(=sum of cnt_t slices) -> rp, block sums
__launch_bounds__(1024)
__global__ void k_scan1(const int* __restrict__ cnt_t, int* __restrict__ rp,
                        int* __restrict__ bsum, int N) {
    __shared__ int sc[1024];
    int t = threadIdx.x;
    int i = blockIdx.x * 1024 + t;
    int v = 0;
    if (i < N)
        v = cnt_t[i] + cnt_t[(size_t)N + i] + cnt_t[2 * (size_t)N + i];
    sc[t] = v;
    __syncthreads();
    for (int off = 1; off < 1024; off <<= 1) {
        int u = (t >= off) ? sc[t - off] : 0;
        __syncthreads();
        sc[t] += u;
        __syncthreads();
    }
    if (i < N) rp[i] = sc[t] - v;  // exclusive within block
    if (t == 1023) bsum[blockIdx.x] = sc[t];
}

// level 2: exclusive scan of block sums (nb <= 1024), in place
__launch_bounds__(1024)
__global__ void k_scan2(int* __restrict__ bsum, int nb) {
    __shared__ int sc[1024];
    int t = threadIdx.x;
    int v = (t < nb) ? bsum[t] : 0;
    sc[t] = v;
    __syncthreads();
    for (int off = 1; off < 1024; off <<= 1) {
        int u = (t >= off) ? sc[t - off] : 0;
        __syncthreads();
        sc[t] += u;
        __syncthreads();
    }
    if (t < nb) bsum[t] = sc[t] - v;
}

// level 3: rp4[d] = (start, start+c0, start+c0+c1, end) + cntp build
__global__ void k_scan3(const int* __restrict__ rp, const int* __restrict__ bsum,
                        const int* __restrict__ cnt_t, float4* __restrict__ cntp,
                        int4* __restrict__ rp4, int N) {
    int i = blockIdx.x * 256 + threadIdx.x;
    if (i < N) {
        int start = rp[i] + bsum[i >> 10];
        int c0 = cnt_t[i];
        int c1 = cnt_t[(size_t)N + i];
        int c2 = cnt_t[2 * (size_t)N + i];
        rp4[i] = make_int4(start, start + c0, start + c0 + c1, start + c0 + c1 + c2);
        float4 v;
        v.x = (float)c0; v.y = (float)c1; v.z = (float)c2;
        v.w = 1.0f / fmaxf((float)(c0 + c1 + c2), 1.0f);
        cntp[i] = v;
    }
}

// type-sorted CSR fill: e2[slot] = (src, pos); type base straight from rp4
__global__ void k_fill(const int* __restrict__ ei, const int* __restrict__ et,
                       const int* __restrict__ ep, const int4* __restrict__ rp4,
                       int* __restrict__ cur3, int2* __restrict__ e2, int E, int N) {
    int e = blockIdx.x * 256 + threadIdx.x;
    if (e < E) {
        int d = ei[E + e];
        int t = et[e];
        int4 r4 = rp4[d];
        int base = (t == 0) ? r4.x : ((t == 1) ? r4.y : r4.z);
        int pos = atomicAdd(&cur3[(size_t)t * N + d], 1);
        e2[base + pos] = make_int2(ei[e], ep[e]);
    }
}

__global__ void k_gate(const float* __restrict__ pe, const float* __restrict__ Wg,
                       const float* __restrict__ bg, f16* __restrict__ gb) {
    int p = blockIdx.x;
    int j = threadIdx.x;
    float acc = bg[j];
    #pragma unroll 8
    for (int k = 0; k < PD; ++k) acc += pe[p * PD + k] * Wg[k * HD + j];
    gb[p * HD + j] = (f16)(2.0f * sigm(acc));
}

// WtT[t][n][k] = Wt[t][k][n]; W1T[n][k] = W1[k][n]
__global__ void k_prep(const float* __restrict__ Wt, const float* __restrict__ W1,
                       f16* __restrict__ WtT, f16* __restrict__ W1T) {
    const int SZ = 3 * HD * HD;
    int id = blockIdx.x * 256 + threadIdx.x;
    if (id < SZ) {
        int t = id / (HD * HD), rem = id % (HD * HD);
        int n = rem / HD, k = rem % HD;
        WtT[id] = (f16)Wt[t * HD * HD + k * HD + n];
    } else if (id < SZ + 2 * HD * HD) {
        int rem = id - SZ;
        int n = rem / (2 * HD), k = rem % (2 * HD);
        W1T[rem] = (f16)W1[k * HD + n];
    }
}

// Wcat [512 rows j][256 k]
__global__ void k_prepW(const float* __restrict__ Wih, const float* __restrict__ Whh,
                        f16* __restrict__ Wcat) {
    int id = blockIdx.x * 256 + threadIdx.x;
    if (id < 512 * 256) {
        int j = id >> 8, k = id & 255;
        float v;
        if (j < 256)      v = (k < 128) ? Wih[j * 128 + k] : Whh[j * 128 + (k - 128)];
        else if (j < 384) v = (k < 128) ? Wih[j * 128 + k] : 0.0f;
        else              v = (k < 128) ? 0.0f : Whh[(j - 128) * 128 + (k - 128)];
        Wcat[id] = (f16)v;
    }
}

__global__ void k_init(const int* __restrict__ xidx, const float* __restrict__ sel,
                       const float* __restrict__ emb, f16* __restrict__ h, int N) {
    int id = blockIdx.x * 256 + threadIdx.x;
    if (id < N * HD) {
        int n = id >> 7, j = id & 127;
        float v = (j < EMBD) ? emb[(size_t)xidx[n] * EMBD + j]
                             : sel[(size_t)n * SELD + (j - EMBD)];
        h[id] = (f16)v;
    }
}

// ---------------- per-iteration kernel A: gather + message matmul ----------------
// 16 rows/block, 512 thr (8 waves); wave w gathers rows w (lanes 0-31) and w+8
// (lanes 32-63) simultaneously. Type-sorted CSR + prefix-subtract accumulation
// in packed f16.
__launch_bounds__(512, 4)
__global__ void k_agg(const int4* __restrict__ rp4, const int2* __restrict__ e2,
                      const f16* __restrict__ h_in, const f16* __restrict__ gb,
                      const f16* __restrict__ WtT, const float* __restrict__ bt,
                      const float4* __restrict__ cntp, f16* __restrict__ agg, int N) {
    __shared__ f16 S[3 * 16 * 136];
    __shared__ f16 aggL[16 * 136];

    int tid = threadIdx.x;
    int wave = tid >> 6, lane = tid & 63;
    int quad = lane >> 4, m = lane & 15;
    int half = lane >> 5, hl = lane & 31;
    int d0 = blockIdx.x * 16;

    // ---- P1: dual-row gather
    {
        int lrow = wave + half * 8;
        int grow = d0 + lrow;
        bool valid = grow < N;
        int4 r4 = rp4[min(grow, N - 1)];
        int es = r4.x, b1 = r4.y, b2 = r4.z, ee = r4.w;
        if (!valid) ee = es;
        int dg = ee - es;
        int dmax = max(dg, __shfl_xor(dg, 32));
        int nb = (__builtin_amdgcn_readfirstlane(dmax) + 7) >> 3;
        int co = hl * 4;  // 4 f16 cols per lane

        const f16x4 zf = {0, 0, 0, 0};
        f16x4 accA = zf, accB = zf, accC = zf;
        for (int b = 0; b < nb; ++b) {
            int e0 = es + b * 8;
            int2 ev[8];
            #pragma unroll
            for (int j = 0; j < 8; ++j) {
                int idx = max(min(e0 + j, ee - 1), 0);
                ev[j] = e2[idx];
            }
            f16x4 hv[8], gv[8];
            #pragma unroll
            for (int j = 0; j < 8; ++j) {
                hv[j] = *(const f16x4*)(h_in + (size_t)ev[j].x * HD + co);
                gv[j] = *(const f16x4*)(gb + (size_t)ev[j].y * HD + co);
            }
            #pragma unroll
            for (int j = 0; j < 8; ++j) {
                int eidx = e0 + j;
                f16x4 g0 = (eidx < ee) ? gv[j] : zf;   // active mask
                accA += hv[j] * g0;                     // v_pk_fma x2
                f16x4 gB = (eidx >= b1) ? g0 : zf;
                accB += hv[j] * gB;
                f16x4 gC = (eidx >= b2) ? g0 : zf;
                accC += hv[j] * gC;
            }
        }
        f16x4 s0 = accA - accB;   // type-0 sum
        f16x4 s1 = accB - accC;   // type-1 sum
        *(f16x4*)(S + (0 * 16 + lrow) * 136 + co) = s0;
        *(f16x4*)(S + (1 * 16 + lrow) * 136 + co) = s1;
        *(f16x4*)(S + (2 * 16 + lrow) * 136 + co) = accC;
    }
    __syncthreads();

    // ---- P2: message matmul: wave w -> cols w*16..+15
    {
        int col = wave * 16 + m;
        f32x4 acc = {0.f, 0.f, 0.f, 0.f};
        #pragma unroll
        for (int t = 0; t < 3; ++t)
            #pragma unroll
            for (int c = 0; c < 4; ++c) {
                f16x8 a = *(const f16x8*)(S + (t * 16 + m) * 136 + c * 32 + quad * 8);
                f16x8 b = *(const f16x8*)(WtT + ((size_t)t * HD + col) * HD + c * 32 + quad * 8);
                acc = __builtin_amdgcn_mfma_f32_16x16x32_f16(a, b, acc, 0, 0, 0);
            }
        float bt0 = bt[col], bt1 = bt[HD + col], bt2 = bt[2 * HD + col];
        #pragma unroll
        for (int r = 0; r < 4; ++r) {
            int lr = quad * 4 + r;
            int dd2 = min(d0 + lr, N - 1);
            float4 cp = cntp[dd2];
            float v = (acc[r] + cp.x * bt0 + cp.y * bt1 + cp.z * bt2) * cp.w;
            aggL[lr * 136 + col] = (f16)v;
        }
    }
    __syncthreads();

    // ---- coalesced copy-out: thread t -> row t>>5, 4 f16 at (t&31)*4
    {
        int row = tid >> 5, ch = tid & 31;
        if (d0 + row < N) {
            f16x4 v = *(const f16x4*)(aggL + row * 136 + ch * 4);
            *(f16x4*)(agg + (size_t)(d0 + row) * HD + ch * 4) = v;
        }
    }
}

// ---------------- per-iteration kernel B: GRU as 64-row GEMM ----------------
// A = [agg|h] (64x256, LDS), B = Wcat (global, L2-hot). A-frags streamed from
// LDS inside the K-loop (low VGPR -> 4 waves/SIMD). Wave w owns out col block
// j = w*16+m for all gates.
__launch_bounds__(512, 4)
__global__ void k_gru(const f16* __restrict__ agg, const f16* __restrict__ h_in,
                      const f16* __restrict__ Wcat, const float* __restrict__ bih,
                      const float* __restrict__ bhh, f16* __restrict__ h_out, int N) {
    __shared__ f16 AL[64 * 264];  // A tile, stride 264 (bank-spread)

    int tid = threadIdx.x;
    int wave = tid >> 6, lane = tid & 63;
    int quad = lane >> 4, m = lane & 15;
    int d0 = blockIdx.x * 64;

    // ---- stage A = [agg | h]
    {
        int rsub = tid >> 5;   // 0..15
        int ch = tid & 31;     // 0..31
        #pragma unroll
        for (int i = 0; i < 4; ++i) {
            int row = i * 16 + rsub;
            int grow = min(d0 + row, N - 1);
            f16x8 v;
            if (ch < 16) v = *(const f16x8*)(agg + (size_t)grow * HD + ch * 8);
            else         v = *(const f16x8*)(h_in + (size_t)grow * HD + (ch - 16) * 8);
            *(f16x8*)(AL + row * 264 + ch * 8) = v;
        }
    }
    __syncthreads();

    int j = wave * 16 + m;  // output column within each gate
    f32x4 ar[4], az[4], an[4], ah[4];
    const f32x4 z4 = {0.f, 0.f, 0.f, 0.f};
    #pragma unroll
    for (int tau = 0; tau < 4; ++tau) { ar[tau] = z4; az[tau] = z4; an[tau] = z4; ah[tau] = z4; }

    #pragma unroll
    for (int c = 0; c < 8; ++c) {
        f16x8 br = *(const f16x8*)(Wcat + (size_t)j * 256 + c * 32 + quad * 8);
        f16x8 bz = *(const f16x8*)(Wcat + (size_t)(128 + j) * 256 + c * 32 + quad * 8);
        f16x8 bn = (c < 4)
            ? *(const f16x8*)(Wcat + (size_t)(256 + j) * 256 + c * 32 + quad * 8)
            : *(const f16x8*)(Wcat + (size_t)(384 + j) * 256 + c * 32 + quad * 8);
        #pragma unroll
        for (int tau = 0; tau < 4; ++tau) {
            f16x8 a = *(const f16x8*)(AL + (tau * 16 + m) * 264 + c * 32 + quad * 8);
            ar[tau] = __builtin_amdgcn_mfma_f32_16x16x32_f16(a, br, ar[tau], 0, 0, 0);
            az[tau] = __builtin_amdgcn_mfma_f32_16x16x32_f16(a, bz, az[tau], 0, 0, 0);
            if (c < 4) an[tau] = __builtin_amdgcn_mfma_f32_16x16x32_f16(a, bn, an[tau], 0, 0, 0);
            else       ah[tau] = __builtin_amdgcn_mfma_f32_16x16x32_f16(a, bn, ah[tau], 0, 0, 0);
        }
    }

    // ---- GRU epilogue (fast transcendentals)
    float b_r  = bih[j] + bhh[j];
    float b_z  = bih[HD + j] + bhh[HD + j];
    float b_in = bih[2 * HD + j];
    float b_hn = bhh[2 * HD + j];
    float hp[4][4];
    #pragma unroll
    for (int tau = 0; tau < 4; ++tau)
        #pragma unroll
        for (int r = 0; r < 4; ++r) {
            int row = tau * 16 + quad * 4 + r;
            float hval = (float)AL[row * 264 + 128 + j];
            float rr = sigm(ar[tau][r] + b_r);
            float zz = sigm(az[tau][r] + b_z);
            float nn = tanh_f(an[tau][r] + b_in + rr * (ah[tau][r] + b_hn));
            hp[tau][r] = (1.0f - zz) * nn + zz * hval;
        }
    __syncthreads();  // all AL reads done before reuse as output staging

    #pragma unroll
    for (int tau = 0; tau < 4; ++tau)
        #pragma unroll
        for (int r = 0; r < 4; ++r)
            AL[(tau * 16 + quad * 4 + r) * 132 + j] = (f16)hp[tau][r];
    __syncthreads();

    // ---- coalesced copy-out
    {
        int rsub = tid >> 5, ch = tid & 31;
        #pragma unroll
        for (int i = 0; i < 4; ++i) {
            int row = i * 16 + rsub;
            if (d0 + row < N) {
                f16x4 v = *(const f16x4*)(AL + row * 132 + ch * 4);
                *(f16x4*)(h_out + (size_t)(d0 + row) * HD + ch * 4) = v;
            }
        }
    }
}

// feats=[h|emb[x]|sel] (f16 frags) @ W1T (MFMA) -> relu -> @W2 + b2
__launch_bounds__(256)
__global__ void k_final(const f16* __restrict__ h_f, const int* __restrict__ xidx,
                        const float* __restrict__ sel, const float* __restrict__ emb,
                        const f16* __restrict__ W1T, const float* __restrict__ b1,
                        const float* __restrict__ W2, const float* __restrict__ b2,
                        float* __restrict__ out, int N) {
    __shared__ float red[4][16];
    int tid = threadIdx.x;
    int wave = tid >> 6, lane = tid & 63;
    int quad = lane >> 4, m = lane & 15;
    int row0 = blockIdx.x * 16;
    int arow = min(row0 + m, N - 1);
    int xi = xidx[arow];

    f16x8 fa[8];
    #pragma unroll
    for (int c = 0; c < 4; ++c)
        fa[c] = *(const f16x8*)(h_f + (size_t)arow * HD + c * 32 + quad * 8);
    #pragma unroll
    for (int c = 4; c < 7; ++c) {
        const float* ep = emb + (size_t)xi * EMBD + (c - 4) * 32 + quad * 8;
        #pragma unroll
        for (int jj = 0; jj < 8; ++jj) fa[c][jj] = (f16)ep[jj];
    }
    {
        const float* sp = sel + (size_t)arow * SELD + quad * 8;
        #pragma unroll
        for (int jj = 0; jj < 8; ++jj) fa[7][jj] = (f16)sp[jj];
    }

    f32x4 acc[2];
    const f32x4 z4 = {0.f, 0.f, 0.f, 0.f};
    acc[0] = z4; acc[1] = z4;
    #pragma unroll
    for (int s = 0; s < 2; ++s) {
        int c0 = (wave * 2 + s) * 16;
        #pragma unroll
        for (int c = 0; c < 8; ++c) {
            f16x8 b = *(const f16x8*)(W1T + (size_t)(c0 + m) * (2 * HD) + c * 32 + quad * 8);
            acc[s] = __builtin_amdgcn_mfma_f32_16x16x32_f16(fa[c], b, acc[s], 0, 0, 0);
        }
    }

    float psum[4] = {0.f, 0.f, 0.f, 0.f};
    #pragma unroll
    for (int s = 0; s < 2; ++s) {
        int col = (wave * 2 + s) * 16 + m;
        float b1v = b1[col], w2v = W2[col];
        #pragma unroll
        for (int r = 0; r < 4; ++r)
            psum[r] += fmaxf(acc[s][r] + b1v, 0.0f) * w2v;
    }
    #pragma unroll
    for (int off = 1; off < 16; off <<= 1)
        #pragma unroll
        for (int r = 0; r < 4; ++r) psum[r] += __shfl_xor(psum[r], off);

    if (m == 0) {
        #pragma unroll
        for (int r = 0; r < 4; ++r) red[wave][quad * 4 + r] = psum[r];
    }
    __syncthreads();
    if (tid < 16) {
        int row = row0 + tid;
        if (row < N) out[row] = red[0][tid] + red[1][tid] + red[2][tid] + red[3][tid] + b2[0];
    }
}

// ---------------- launcher ----------------

extern "C" void kernel_launch(void* const* d_in, const int* in_sizes, int n_in,
                              void* d_out, int out_size, void* d_ws, size_t ws_size,
                              hipStream_t stream) {
    const int*   xidx = (const int*)d_in[0];
    const float* sel  = (const float*)d_in[1];
    const int*   ei   = (const int*)d_in[2];
    const int*   et   = (const int*)d_in[3];
    const int*   ep   = (const int*)d_in[4];
    const float* emb  = (const float*)d_in[5];
    const float* pe   = (const float*)d_in[6];
    const float* Wg   = (const float*)d_in[7];
    const float* bg   = (const float*)d_in[8];
    const float* Wt   = (const float*)d_in[9];
    const float* bt   = (const float*)d_in[10];
    const float* Wih  = (const float*)d_in[11];
    const float* Whh  = (const float*)d_in[12];
    const float* bih  = (const float*)d_in[13];
    const float* bhh  = (const float*)d_in[14];
    const float* W1   = (const float*)d_in[15];
    const float* b1   = (const float*)d_in[16];
    const float* W2   = (const float*)d_in[17];
    const float* b2   = (const float*)d_in[18];

    const int N = in_sizes[0];
    const int E = in_sizes[3];
    const size_t NH = (size_t)N * HD;

    char* p = (char*)d_ws;
    f16*    hbf0  = (f16*)p;    p += NH * 2;
    f16*    hbf1  = (f16*)p;    p += NH * 2;
    f16*    aggb  = (f16*)p;    p += NH * 2;
    f16*    gb    = (f16*)p;    p += (size_t)NPOS * HD * 2;
    f16*    WtT   = (f16*)p;    p += 3 * HD * HD * 2;
    f16*    Wcat  = (f16*)p;    p += 512 * 256 * 2;
    f16*    W1T   = (f16*)p;    p += 2 * HD * HD * 2;
    float4* cntp  = (float4*)p; p += (size_t)N * 16;
    int4*   rp4   = (int4*)p;   p += (size_t)N * 16;
    int* cnt_t  = (int*)p; p += 3 * (size_t)N * 4;
    int* rp     = (int*)p; p += (size_t)N * 4;
    int* cur3   = (int*)p; p += 3 * (size_t)N * 4;
    int* bsum   = (int*)p; p += 1024 * 4;
    int2* e2    = (int2*)p;

    // ---- setup ----
    hipMemsetAsync(cnt_t, 0, 3 * (size_t)N * sizeof(int), stream);
    hipMemsetAsync(cur3, 0, 3 * (size_t)N * sizeof(int), stream);
    k_deg<<<(E + 255) / 256, 256, 0, stream>>>(ei, et, cnt_t, E, N);
    const int nb1 = (N + 1023) / 1024;
    k_scan1<<<nb1, 1024, 0, stream>>>(cnt_t, rp, bsum, N);
    k_scan2<<<1, 1024, 0, stream>>>(bsum, nb1);
    k_scan3<<<(N + 255) / 256, 256, 0, stream>>>(rp, bsum, cnt_t, cntp, rp4, N);
    k_fill<<<(E + 255) / 256, 256, 0, stream>>>(ei, et, ep, rp4, cur3, e2, E, N);
    k_gate<<<NPOS, HD, 0, stream>>>(pe, Wg, bg, gb);
    k_prep<<<(3 * HD * HD + 2 * HD * HD + 255) / 256, 256, 0, stream>>>(Wt, W1, WtT, W1T);
    k_prepW<<<512, 256, 0, stream>>>(Wih, Whh, Wcat);
    k_init<<<(N * HD + 255) / 256, 256, 0, stream>>>(xidx, sel, emb, hbf0, N);

    const int gA = (N + 15) / 16;
    const int gG = (N + 63) / 64;
    const f16* hin = hbf0;
    f16* hout = hbf1;
    for (int it = 0; it < GITERS; ++it) {
        k_agg<<<gA, 512, 0, stream>>>(rp4, e2, hin, gb, WtT, bt, cntp, aggb, N);
        k_gru<<<gG, 512, 0, stream>>>(aggb, hin, Wcat, bih, bhh, hout, N);
        const f16* tmp = hout;
        hout = (f16*)hin;
        hin = tmp;
    }

    const int gF = (N + 15) / 16;
    k_final<<<gF, 256, 0, stream>>>(hin, xidx, sel, emb, W1T, b1, W2, b2, (float*)d_out, N);
}